// Round 6
// baseline (278.182 us; speedup 1.0000x reference)
//
#include <hip/hip_runtime.h>
#include <stdint.h>

#define LOG2E 1.44269504088896340736f

typedef __bf16 v8bf __attribute__((ext_vector_type(8)));
typedef float f32x4 __attribute__((ext_vector_type(4)));
typedef float f32x16 __attribute__((ext_vector_type(16)));
typedef unsigned int v4u __attribute__((ext_vector_type(4)));
typedef unsigned int v2u __attribute__((ext_vector_type(2)));

// ---------- helpers ----------
__device__ __forceinline__ unsigned short f2bf(float f) {
  union { float f; uint32_t u; } v; v.f = f;
  uint32_t u = v.u;
  uint32_t r = (u + 0x7FFFu + ((u >> 16) & 1u)) >> 16;   // RN-even
  return (unsigned short)r;
}
__device__ __forceinline__ float bf2f(unsigned short h) {
  union { uint32_t u; float f; } v; v.u = ((uint32_t)h) << 16;
  return v.f;
}
__device__ __forceinline__ void gll16(const void* g, void* l) {
  __builtin_amdgcn_global_load_lds(
      (const __attribute__((address_space(1))) unsigned int*)g,
      (__attribute__((address_space(3))) unsigned int*)l, 16, 0, 0);
}
__device__ __forceinline__ uint32_t pk2(float a, float b) {
  union { __bf16 h[2]; uint32_t u; } x;
  x.h[0] = (__bf16)a; x.h[1] = (__bf16)b;
  return x.u;
}

// ---------- prep: x -> [hi | lo | hi]  (4096 x 2304 bf16) ----------
__global__ void prep_a(const float* __restrict__ x, unsigned short* __restrict__ Acat) {
  int n = blockIdx.x * 256 + threadIdx.x;   // 0..767
  int m = blockIdx.y;                       // 0..4095
  float v = x[(size_t)m * 768 + n];
  unsigned short H = f2bf(v);
  unsigned short L = f2bf(v - bf2f(H));
  size_t base = (size_t)m * 2304;
  Acat[base + n] = H;
  Acat[base + 768 + n] = L;
  Acat[base + 1536 + n] = H;
}

// ---------- prep: Wqkv^T cat -> rows n: [Whi | Whi | Wlo] (2304 x 2304 bf16) ----------
__global__ void prep_bqkv(const float* __restrict__ W, unsigned short* __restrict__ BT) {
  int k = blockIdx.x * 256 + threadIdx.x;   // 0..767
  int n = blockIdx.y;                       // 0..2303
  float v = W[(size_t)k * 2304 + n];
  unsigned short H = f2bf(v);
  unsigned short L = f2bf(v - bf2f(H));
  size_t base = (size_t)n * 2304;
  BT[base + k] = H;
  BT[base + 768 + k] = H;
  BT[base + 1536 + k] = L;
}

// ---------- prep: Wout^T single bf16 (768 x 768) ----------
__global__ void prep_wout(const float* __restrict__ W, unsigned short* __restrict__ BT) {
  int k = blockIdx.x * 256 + threadIdx.x;   // 0..767
  int n = blockIdx.y;                       // 0..767
  BT[(size_t)n * 768 + k] = f2bf(W[(size_t)k * 768 + n]);
}

// ---------- GEMM: C[M,N] = A[M,K](bf16) * B^T[N,K](bf16) + bias[N], fp32 out ----------
// Flat grid = (N/128)*32 blocks, M fixed at 4096 (32 y-tiles).
// XCD swizzle (id%8 round-robin): ytile = (f&7)*4 + (slot&3), xtile = slot>>2
// -> each XCD owns a 4-row A-stripe (2.4 MB, L2-resident) across all x-tiles.
__global__ __launch_bounds__(256) void gemm_bf16_128(
    const unsigned short* __restrict__ A, const unsigned short* __restrict__ B,
    const float* __restrict__ bias, float* __restrict__ C,
    int M, int N, int K) {
  __shared__ unsigned short As[128 * 32];
  __shared__ unsigned short Bs[128 * 32];
  const int t = threadIdx.x;
  const int f = blockIdx.x, slot = f >> 3;
  const int m0 = ((f & 7) * 4 + (slot & 3)) * 128;
  const int n0 = (slot >> 2) * 128;
  const int w = t >> 6, l = t & 63;
  const int wm = (w >> 1) * 64, wn = (w & 1) * 64;
  const int lr = l & 15, lg = l >> 4;
  f32x4 acc[4][4] = {};
  const int nk = K >> 5;
  for (int kt = 0; kt < nk; ++kt) {
    const int k0 = kt << 5;
    {
      const int c0 = t, c1 = t + 256;
      gll16(A + (size_t)(m0 + (c0 >> 2)) * K + k0 + ((c0 & 3) << 3), &As[c0 * 8]);
      gll16(A + (size_t)(m0 + (c1 >> 2)) * K + k0 + ((c1 & 3) << 3), &As[c1 * 8]);
      gll16(B + (size_t)(n0 + (c0 >> 2)) * K + k0 + ((c0 & 3) << 3), &Bs[c0 * 8]);
      gll16(B + (size_t)(n0 + (c1 >> 2)) * K + k0 + ((c1 & 3) << 3), &Bs[c1 * 8]);
    }
    __syncthreads();
    v8bf a[4], b[4];
#pragma unroll
    for (int i = 0; i < 4; i++) {
      a[i] = *(const v8bf*)&As[(wm + i * 16 + lr) * 32 + lg * 8];
      b[i] = *(const v8bf*)&Bs[(wn + i * 16 + lr) * 32 + lg * 8];
    }
#pragma unroll
    for (int i = 0; i < 4; i++)
#pragma unroll
      for (int j = 0; j < 4; j++)
        acc[i][j] = __builtin_amdgcn_mfma_f32_16x16x32_bf16(a[i], b[j], acc[i][j], 0, 0, 0);
    __syncthreads();
  }
#pragma unroll
  for (int i = 0; i < 4; i++) {
#pragma unroll
    for (int j = 0; j < 4; j++) {
      const int col = n0 + wn + j * 16 + lr;
      const float bv = bias[col];
#pragma unroll
      for (int r = 0; r < 4; r++) {
        const int row = m0 + wm + i * 16 + lg * 4 + r;
        C[(size_t)row * N + col] = acc[i][j][r] + bv;
      }
    }
  }
}

// ---------- split qkv fp32 -> Qcat/Kcat (split-bf16, *8 folded into Q), V^T bf16 ----------
__global__ void split_qkv(const float* __restrict__ qkv,
                          unsigned short* __restrict__ Qc,
                          unsigned short* __restrict__ Kc,
                          unsigned short* __restrict__ VT) {
  int n = blockIdx.x * 256 + threadIdx.x;   // 0..2303
  int m = blockIdx.y;                       // 0..4095
  float val = qkv[(size_t)m * 2304 + n];
  int h = n / 192;
  int j = n - h * 192;
  int b = m >> 11, p = m & 2047;
  int bh = b * 12 + h;
  size_t base = (size_t)bh * 2048 * 192 + (size_t)p * 192;
  if (j < 64) {
    float v8v = val * 8.0f;                 // fold logits *= sqrt(64) (exact: pow2)
    unsigned short H = f2bf(v8v);
    unsigned short L = f2bf(v8v - bf2f(H));
    Qc[base + j] = H; Qc[base + 64 + j] = L; Qc[base + 128 + j] = H;
  } else if (j < 128) {
    int d = j - 64;
    unsigned short H = f2bf(val);
    unsigned short L = f2bf(val - bf2f(H));
    Kc[base + d] = H; Kc[base + 64 + d] = H; Kc[base + 128 + d] = L;
  } else {
    int d = j - 128;
    VT[(size_t)bh * 64 * 2048 + (size_t)d * 2048 + p] = f2bf(val);
  }
}

// ---------- flash attention: 32x32 swapped-QK^T, in-register softmax ----------
// Flat grid 1536 = 8 xcd x 12 pairGroups x 16 q-tiles; split-K x4 (8 kt each).
// XCD-grouping swizzle: all 16 q-tile blocks of one (bh,split) pair land on one
// XCD (id%8 round-robin) -> K/V fetched ~once into that L2, reused 16x.
// s = mfma(A=K, B=Q): lane owns q-col (l&31); softmax lane-local + 1 permlane.
// P -> PV A-frags in-register via cvt_pk + permlane32_swap (T12).
// K/V reg-staged (T14), LDS XOR-swizzled (^(row&7)<<3 on elem idx).
__global__ __launch_bounds__(256) void attn(
    const unsigned short* __restrict__ Qc, const unsigned short* __restrict__ Kc,
    const unsigned short* __restrict__ VT,
    float* __restrict__ Op, float* __restrict__ Ml) {
  __shared__ __align__(16) unsigned short Ks[64 * 192];
  __shared__ __align__(16) unsigned short Vs[64 * 64];
  __shared__ float Al[4][32];
  const int t = threadIdx.x, w = t >> 6, l = t & 63;
  const int lq = l & 31, hi = l >> 5;
  const int f = blockIdx.x;
  const int xcd = f & 7, slot = f >> 3;
  const int p = xcd + 8 * (slot >> 4);      // 0..95: (bh,split) pair
  const int bh = p >> 2, zsplit = p & 3;
  const int q0 = (slot & 15) * 128;
  const int qw0 = q0 + w * 32;
  const int ktBase = zsplit * 8;            // 8 K-tiles per split
  const unsigned short* Qb = Qc + (size_t)bh * 2048 * 192;
  const unsigned short* Kb = Kc + (size_t)bh * 2048 * 192;
  const unsigned short* Vb = VT + (size_t)bh * 64 * 2048;

  // hoisted swizzled LDS write offsets (element units)
  int kwofs[6];
#pragma unroll
  for (int i = 0; i < 6; i++) {
    int c = t + i * 256;                    // 16B chunk id; 24 chunks per 192-elem row
    int row = c / 24, cc = c - row * 24;
    kwofs[i] = (row * 192 + cc * 8) ^ ((row & 7) << 3);
  }
  int vwofs[2];
#pragma unroll
  for (int i = 0; i < 2; i++) {
    int c = t + i * 256;                    // 8 chunks per 64-elem V^T row
    int d = c >> 3, part = c & 7;
    vwofs[i] = (d * 64 + part * 8) ^ ((d & 7) << 3);
  }
  // linear global source pointers (coalesced), bumped per kt
  const char* gK = (const char*)Kb + (size_t)ktBase * 24576 + (size_t)t * 16;
  const char* gV = (const char*)Vb + (size_t)(t >> 3) * 4096 + (size_t)(t & 7) * 16
                   + (size_t)ktBase * 128;

  v4u kreg[6], vreg[2];
#pragma unroll
  for (int i = 0; i < 6; i++) kreg[i] = *(const v4u*)(gK + i * 4096);
#pragma unroll
  for (int i = 0; i < 2; i++) vreg[i] = *(const v4u*)(gV + i * 131072);

  // Q B-frags, resident: lane holds Q[qw0+lq][ks*16 + hi*8 .. +7]
  v8bf qf[12];
#pragma unroll
  for (int ks = 0; ks < 12; ++ks)
    qf[ks] = *(const v8bf*)(Qb + (size_t)(qw0 + lq) * 192 + ks * 16 + hi * 8);

  f32x16 o0 = {}, o1 = {};
  float mrun = -1e30f, lsum = 0.f;
  const int sx = (l & 7) << 3;              // read swizzle: rows are lq / lq+32 / d

  for (int kt = 0; kt < 8; ++kt) {
    // drain staged regs to LDS
#pragma unroll
    for (int i = 0; i < 6; i++) *(v4u*)&Ks[kwofs[i]] = kreg[i];
#pragma unroll
    for (int i = 0; i < 2; i++) *(v4u*)&Vs[vwofs[i]] = vreg[i];
    __syncthreads();

    // issue next tile's loads — fly during this tile's compute
    if (kt < 7) {
      gK += 24576; gV += 128;
#pragma unroll
      for (int i = 0; i < 6; i++) kreg[i] = *(const v4u*)(gK + i * 4096);
#pragma unroll
      for (int i = 0; i < 2; i++) vreg[i] = *(const v4u*)(gV + i * 131072);
    }

    // S^T = K Q^T : s0 = keys 0-31, s1 = keys 32-63 (cols = q)
    f32x16 s0 = {}, s1 = {};
    __builtin_amdgcn_s_setprio(1);
#pragma unroll
    for (int ks = 0; ks < 12; ++ks) {
      v8bf ka = *(const v8bf*)&Ks[((lq) * 192 + ks * 16 + hi * 8) ^ sx];
      v8bf kb = *(const v8bf*)&Ks[((lq + 32) * 192 + ks * 16 + hi * 8) ^ sx];
      s0 = __builtin_amdgcn_mfma_f32_32x32x16_bf16(ka, qf[ks], s0, 0, 0, 0);
      s1 = __builtin_amdgcn_mfma_f32_32x32x16_bf16(kb, qf[ks], s1, 0, 0, 0);
    }
    __builtin_amdgcn_s_setprio(0);

    // ---- lane-local softmax over 32 values + one half-swap ----
    float tm[16];
#pragma unroll
    for (int i = 0; i < 16; i++) tm[i] = fmaxf(s0[i], s1[i]);
#pragma unroll
    for (int i = 0; i < 8; i++) tm[i] = fmaxf(tm[i], tm[i + 8]);
#pragma unroll
    for (int i = 0; i < 4; i++) tm[i] = fmaxf(tm[i], tm[i + 4]);
    float pmax = fmaxf(fmaxf(tm[0], tm[1]), fmaxf(tm[2], tm[3]));
    {
      v2u r = __builtin_amdgcn_permlane32_swap(__float_as_uint(pmax),
                                               __float_as_uint(pmax), false, false);
      pmax = fmaxf(__uint_as_float(r.x), __uint_as_float(r.y));
    }

    // T13 defer-max (THR=8)
    if (__any(pmax > mrun + 8.f)) {
      float mnew = fmaxf(mrun, pmax);
      float a = __builtin_exp2f((mrun - mnew) * LOG2E);
      mrun = mnew;
      lsum *= a;
      if (!hi) Al[w][lq] = a;
      asm volatile("s_waitcnt lgkmcnt(0)" ::: "memory");
#pragma unroll
      for (int r = 0; r < 16; r++) {
        float ar = Al[w][(r & 3) + 8 * (r >> 2) + 4 * hi];
        o0[r] *= ar; o1[r] *= ar;
      }
    }

    // P = exp(S - m), accumulate row-sum, build PV A-frags in-register
    const float mL = mrun * LOG2E;
    float p2[16];
    float ps = 0.f;
    uint32_t paw[4][4];                      // [ks][word]
    // s0 -> keys 0-31 -> PV ks=0,1
#pragma unroll
    for (int i = 0; i < 16; i++) { p2[i] = __builtin_exp2f(s0[i] * LOG2E - mL); ps += p2[i]; }
    {
      v2u r0 = __builtin_amdgcn_permlane32_swap(pk2(p2[0], p2[1]), pk2(p2[4], p2[5]), false, false);
      v2u r1 = __builtin_amdgcn_permlane32_swap(pk2(p2[2], p2[3]), pk2(p2[6], p2[7]), false, false);
      paw[0][0] = r0.x; paw[0][2] = r0.y; paw[0][1] = r1.x; paw[0][3] = r1.y;
      v2u r2 = __builtin_amdgcn_permlane32_swap(pk2(p2[8], p2[9]), pk2(p2[12], p2[13]), false, false);
      v2u r3 = __builtin_amdgcn_permlane32_swap(pk2(p2[10], p2[11]), pk2(p2[14], p2[15]), false, false);
      paw[1][0] = r2.x; paw[1][2] = r2.y; paw[1][1] = r3.x; paw[1][3] = r3.y;
    }
    // s1 -> keys 32-63 -> PV ks=2,3
#pragma unroll
    for (int i = 0; i < 16; i++) { p2[i] = __builtin_exp2f(s1[i] * LOG2E - mL); ps += p2[i]; }
    {
      v2u r0 = __builtin_amdgcn_permlane32_swap(pk2(p2[0], p2[1]), pk2(p2[4], p2[5]), false, false);
      v2u r1 = __builtin_amdgcn_permlane32_swap(pk2(p2[2], p2[3]), pk2(p2[6], p2[7]), false, false);
      paw[2][0] = r0.x; paw[2][2] = r0.y; paw[2][1] = r1.x; paw[2][3] = r1.y;
      v2u r2 = __builtin_amdgcn_permlane32_swap(pk2(p2[8], p2[9]), pk2(p2[12], p2[13]), false, false);
      v2u r3 = __builtin_amdgcn_permlane32_swap(pk2(p2[10], p2[11]), pk2(p2[14], p2[15]), false, false);
      paw[3][0] = r2.x; paw[3][2] = r2.y; paw[3][1] = r3.x; paw[3][3] = r3.y;
    }
    {
      v2u r = __builtin_amdgcn_permlane32_swap(__float_as_uint(ps),
                                               __float_as_uint(ps), false, false);
      lsum += __uint_as_float(r.x) + __uint_as_float(r.y);
    }

    // O += P V  (B-frags from Vs rows = d, contiguous along keys)
    __builtin_amdgcn_s_setprio(1);
#pragma unroll
    for (int ks = 0; ks < 4; ++ks) {
      union { uint32_t u[4]; v8bf v; } pa;
      pa.u[0] = paw[ks][0]; pa.u[1] = paw[ks][1];
      pa.u[2] = paw[ks][2]; pa.u[3] = paw[ks][3];
      v8bf v0 = *(const v8bf*)&Vs[((lq) * 64 + ks * 16 + hi * 8) ^ sx];
      v8bf v1 = *(const v8bf*)&Vs[((lq + 32) * 64 + ks * 16 + hi * 8) ^ sx];
      o0 = __builtin_amdgcn_mfma_f32_32x32x16_bf16(pa.v, v0, o0, 0, 0, 0);
      o1 = __builtin_amdgcn_mfma_f32_32x32x16_bf16(pa.v, v1, o1, 0, 0, 0);
    }
    __builtin_amdgcn_s_setprio(0);
    __syncthreads();
  }

  // epilogue: partial (unnormalized) O + (m,l) per q-row
  const size_t S = (size_t)24 * 2048;
  const size_t srow = (size_t)zsplit * S + (size_t)bh * 2048;
  if (!hi) {
    Ml[(srow + qw0 + lq) * 2]     = mrun;
    Ml[(srow + qw0 + lq) * 2 + 1] = lsum;
  }
#pragma unroll
  for (int r = 0; r < 16; r++) {
    const int q = qw0 + (r & 3) + 8 * (r >> 2) + 4 * hi;
    Op[(srow + q) * 64 + lq]      = o0[r];
    Op[(srow + q) * 64 + 32 + lq] = o1[r];
  }
}

// ---------- combine the four split-K partials ----------
__global__ __launch_bounds__(256) void attn_combine(
    const float* __restrict__ Op, const float* __restrict__ Ml,
    __bf16* __restrict__ Oe) {
  const size_t S = (size_t)24 * 2048;
  int row = blockIdx.x * 4 + (threadIdx.x >> 6);   // bh*2048 + q, 0..49151
  int lane = threadIdx.x & 63;
  int bh = row >> 11, q = row & 2047;
  int b = bh / 12, h = bh - b * 12;
  float m[4], lv[4];
#pragma unroll
  for (int s = 0; s < 4; s++) {
    m[s]  = Ml[(s * S + row) * 2];
    lv[s] = Ml[(s * S + row) * 2 + 1];
  }
  float M = fmaxf(fmaxf(m[0], m[1]), fmaxf(m[2], m[3]));
  float num = 0.f, den = 0.f;
  float a[4];
#pragma unroll
  for (int s = 0; s < 4; s++) {
    a[s] = __builtin_exp2f((m[s] - M) * LOG2E);
    den += lv[s] * a[s];
    num += Op[(s * S + row) * 64 + lane] * a[s];
  }
  Oe[((size_t)(b * 2048 + q)) * 768 + h * 64 + lane] = (__bf16)(num / den);
}

// ---------- launcher ----------
extern "C" void kernel_launch(void* const* d_in, const int* in_sizes, int n_in,
                              void* d_out, int out_size, void* d_ws, size_t ws_size,
                              hipStream_t stream) {
  const float* x    = (const float*)d_in[0];
  const float* Wqkv = (const float*)d_in[1];
  const float* bqkv = (const float*)d_in[2];
  const float* Wout = (const float*)d_in[3];
  const float* bout = (const float*)d_in[4];
  float* out = (float*)d_out;
  char* ws = (char*)d_ws;

  unsigned short* Acat  = (unsigned short*)(ws + 0);          // 18.9 MB (dead after gemm_qkv)
  unsigned short* BcatT = (unsigned short*)(ws + 18874368);   // 10.6 MB (dead after gemm_qkv)
  float*          QKV   = (float*)(ws + 29491200);            // 37.7 MB (dead after split_qkv)
  unsigned short* Qcat  = (unsigned short*)(ws + 67239936);   // 18.9 MB
  unsigned short* Kcat  = (unsigned short*)(ws + 86114304);   // 18.9 MB
  unsigned short* VT    = (unsigned short*)(ws + 104988672);  //  6.3 MB
  unsigned short* Oemb  = (unsigned short*)(ws + 111280128);  //  6.3 MB
  unsigned short* WoutT = (unsigned short*)(ws + 117571584);  //  1.2 MB
  // split-K partials alias the dead Acat/BcatT/QKV region:
  float*          Opart = (float*)(ws + 0);                   // 4 x 12.58 MB = 50.3 MB
  float*          Mlpart= (float*)(ws + 50331648);            //  1.6 MB (ends 51.9 MB < 67.2)

  prep_a   <<<dim3(3, 4096), 256, 0, stream>>>(x, Acat);
  prep_bqkv<<<dim3(3, 2304), 256, 0, stream>>>(Wqkv, BcatT);
  prep_wout<<<dim3(3, 768),  256, 0, stream>>>(Wout, WoutT);
  gemm_bf16_128<<<dim3(18 * 32), 256, 0, stream>>>(Acat, BcatT, bqkv, QKV, 4096, 2304, 2304);
  split_qkv<<<dim3(9, 4096), 256, 0, stream>>>(QKV, Qcat, Kcat, VT);
  attn<<<dim3(1536), 256, 0, stream>>>(Qcat, Kcat, VT, Opart, Mlpart);
  attn_combine<<<dim3(12288), 256, 0, stream>>>(Opart, Mlpart, (__bf16*)Oemb);
  gemm_bf16_128<<<dim3(6 * 32), 256, 0, stream>>>(Oemb, WoutT, bout, out, 4096, 768, 768);
}

// Round 7
// 260.804 us; speedup vs baseline: 1.0666x; 1.0666x over previous
//
#include <hip/hip_runtime.h>
#include <stdint.h>

#define LOG2E 1.44269504088896340736f

typedef __bf16 v8bf __attribute__((ext_vector_type(8)));
typedef float f32x4 __attribute__((ext_vector_type(4)));
typedef float f32x16 __attribute__((ext_vector_type(16)));
typedef unsigned int v4u __attribute__((ext_vector_type(4)));
typedef unsigned int v2u __attribute__((ext_vector_type(2)));

// ---------- helpers ----------
__device__ __forceinline__ unsigned short f2bf(float f) {
  union { float f; uint32_t u; } v; v.f = f;
  uint32_t u = v.u;
  uint32_t r = (u + 0x7FFFu + ((u >> 16) & 1u)) >> 16;   // RN-even
  return (unsigned short)r;
}
__device__ __forceinline__ float bf2f(unsigned short h) {
  union { uint32_t u; float f; } v; v.u = ((uint32_t)h) << 16;
  return v.f;
}
__device__ __forceinline__ void gll16(const void* g, void* l) {
  __builtin_amdgcn_global_load_lds(
      (const __attribute__((address_space(1))) unsigned int*)g,
      (__attribute__((address_space(3))) unsigned int*)l, 16, 0, 0);
}
__device__ __forceinline__ uint32_t pk2(float a, float b) {
  union { __bf16 h[2]; uint32_t u; } x;
  x.h[0] = (__bf16)a; x.h[1] = (__bf16)b;
  return x.u;
}

// ---------- prep: x -> [hi | lo | hi]  (4096 x 2304 bf16) ----------
__global__ void prep_a(const float* __restrict__ x, unsigned short* __restrict__ Acat) {
  int n = blockIdx.x * 256 + threadIdx.x;   // 0..767
  int m = blockIdx.y;                       // 0..4095
  float v = x[(size_t)m * 768 + n];
  unsigned short H = f2bf(v);
  unsigned short L = f2bf(v - bf2f(H));
  size_t base = (size_t)m * 2304;
  Acat[base + n] = H;
  Acat[base + 768 + n] = L;
  Acat[base + 1536 + n] = H;
}

// ---------- prep: Wqkv^T cat -> rows n: [Whi | Whi | Wlo] (2304 x 2304 bf16) ----------
__global__ void prep_bqkv(const float* __restrict__ W, unsigned short* __restrict__ BT) {
  int k = blockIdx.x * 256 + threadIdx.x;   // 0..767
  int n = blockIdx.y;                       // 0..2303
  float v = W[(size_t)k * 2304 + n];
  unsigned short H = f2bf(v);
  unsigned short L = f2bf(v - bf2f(H));
  size_t base = (size_t)n * 2304;
  BT[base + k] = H;
  BT[base + 768 + k] = H;
  BT[base + 1536 + k] = L;
}

// ---------- prep: Wout^T single bf16 (768 x 768) ----------
__global__ void prep_wout(const float* __restrict__ W, unsigned short* __restrict__ BT) {
  int k = blockIdx.x * 256 + threadIdx.x;   // 0..767
  int n = blockIdx.y;                       // 0..767
  BT[(size_t)n * 768 + k] = f2bf(W[(size_t)k * 768 + n]);
}

// ---------- GEMM: C[M,N] = A[M,K](bf16) * B^T[N,K](bf16) + bias[N], fp32 out ----------
// Flat grid = (N/128)*32 blocks, M fixed at 4096 (32 y-tiles).
// XCD swizzle (id%8 round-robin): ytile = (f&7)*4 + (slot&3), xtile = slot>>2
__global__ __launch_bounds__(256) void gemm_bf16_128(
    const unsigned short* __restrict__ A, const unsigned short* __restrict__ B,
    const float* __restrict__ bias, float* __restrict__ C,
    int M, int N, int K) {
  __shared__ unsigned short As[128 * 32];
  __shared__ unsigned short Bs[128 * 32];
  const int t = threadIdx.x;
  const int f = blockIdx.x, slot = f >> 3;
  const int m0 = ((f & 7) * 4 + (slot & 3)) * 128;
  const int n0 = (slot >> 2) * 128;
  const int w = t >> 6, l = t & 63;
  const int wm = (w >> 1) * 64, wn = (w & 1) * 64;
  const int lr = l & 15, lg = l >> 4;
  f32x4 acc[4][4] = {};
  const int nk = K >> 5;
  for (int kt = 0; kt < nk; ++kt) {
    const int k0 = kt << 5;
    {
      const int c0 = t, c1 = t + 256;
      gll16(A + (size_t)(m0 + (c0 >> 2)) * K + k0 + ((c0 & 3) << 3), &As[c0 * 8]);
      gll16(A + (size_t)(m0 + (c1 >> 2)) * K + k0 + ((c1 & 3) << 3), &As[c1 * 8]);
      gll16(B + (size_t)(n0 + (c0 >> 2)) * K + k0 + ((c0 & 3) << 3), &Bs[c0 * 8]);
      gll16(B + (size_t)(n0 + (c1 >> 2)) * K + k0 + ((c1 & 3) << 3), &Bs[c1 * 8]);
    }
    __syncthreads();
    v8bf a[4], b[4];
#pragma unroll
    for (int i = 0; i < 4; i++) {
      a[i] = *(const v8bf*)&As[(wm + i * 16 + lr) * 32 + lg * 8];
      b[i] = *(const v8bf*)&Bs[(wn + i * 16 + lr) * 32 + lg * 8];
    }
#pragma unroll
    for (int i = 0; i < 4; i++)
#pragma unroll
      for (int j = 0; j < 4; j++)
        acc[i][j] = __builtin_amdgcn_mfma_f32_16x16x32_bf16(a[i], b[j], acc[i][j], 0, 0, 0);
    __syncthreads();
  }
#pragma unroll
  for (int i = 0; i < 4; i++) {
#pragma unroll
    for (int j = 0; j < 4; j++) {
      const int col = n0 + wn + j * 16 + lr;
      const float bv = bias[col];
#pragma unroll
      for (int r = 0; r < 4; r++) {
        const int row = m0 + wm + i * 16 + lg * 4 + r;
        C[(size_t)row * N + col] = acc[i][j][r] + bv;
      }
    }
  }
}

// ---------- split qkv fp32 -> Qcat/Kcat (split-bf16, *8 folded into Q), V^T bf16 ----------
__global__ void split_qkv(const float* __restrict__ qkv,
                          unsigned short* __restrict__ Qc,
                          unsigned short* __restrict__ Kc,
                          unsigned short* __restrict__ VT) {
  int n = blockIdx.x * 256 + threadIdx.x;   // 0..2303
  int m = blockIdx.y;                       // 0..4095
  float val = qkv[(size_t)m * 2304 + n];
  int h = n / 192;
  int j = n - h * 192;
  int b = m >> 11, p = m & 2047;
  int bh = b * 12 + h;
  size_t base = (size_t)bh * 2048 * 192 + (size_t)p * 192;
  if (j < 64) {
    float v8v = val * 8.0f;                 // fold logits *= sqrt(64) (exact: pow2)
    unsigned short H = f2bf(v8v);
    unsigned short L = f2bf(v8v - bf2f(H));
    Qc[base + j] = H; Qc[base + 64 + j] = L; Qc[base + 128 + j] = H;
  } else if (j < 128) {
    int d = j - 64;
    unsigned short H = f2bf(val);
    unsigned short L = f2bf(val - bf2f(H));
    Kc[base + d] = H; Kc[base + 64 + d] = H; Kc[base + 128 + d] = L;
  } else {
    int d = j - 128;
    VT[(size_t)bh * 64 * 2048 + (size_t)d * 2048 + p] = f2bf(val);
  }
}

// ---------- flash attention: 32x32 swapped-QK^T, LDS DOUBLE-BUFFER, 1 barrier/kt ----------
// Flat grid 768 = 8 xcd x 6 pairGroups x 16 q-tiles; split-K x2 (16 kt each).
// XCD-grouping swizzle: 16 q-tile blocks of one (bh,split) pair share one XCD L2.
// Pipeline: regs hold tile kt+1 while computing kt from buf[kt&1]; ds_writes of
// kt+1 go to buf[kt&1^1] DURING compute (no reader conflict); loads for kt+2
// issued mid-iteration; ONE barrier at end of kt (m233: kills 2-phase stall).
__global__ __launch_bounds__(256) void attn(
    const unsigned short* __restrict__ Qc, const unsigned short* __restrict__ Kc,
    const unsigned short* __restrict__ VT,
    float* __restrict__ Op, float* __restrict__ Ml) {
  __shared__ __align__(16) unsigned short Ks[2][64 * 192];
  __shared__ __align__(16) unsigned short Vs[2][64 * 64];
  __shared__ float Al[4][32];
  const int t = threadIdx.x, w = t >> 6, l = t & 63;
  const int lq = l & 31, hi = l >> 5;
  const int f = blockIdx.x;
  const int xcd = f & 7, slot = f >> 3;
  const int p = xcd + 8 * (slot >> 4);      // 0..47: (bh,split) pair
  const int bh = p >> 1, zsplit = p & 1;
  const int q0 = (slot & 15) * 128;
  const int qw0 = q0 + w * 32;
  const int ktBase = zsplit * 16;           // 16 K-tiles per split
  const int NKT = 16;
  const unsigned short* Qb = Qc + (size_t)bh * 2048 * 192;
  const unsigned short* Kb = Kc + (size_t)bh * 2048 * 192;
  const unsigned short* Vb = VT + (size_t)bh * 64 * 2048;

  // hoisted swizzled LDS write offsets (element units)
  int kwofs[6];
#pragma unroll
  for (int i = 0; i < 6; i++) {
    int c = t + i * 256;                    // 16B chunk id; 24 chunks per 192-elem row
    int row = c / 24, cc = c - row * 24;
    kwofs[i] = (row * 192 + cc * 8) ^ ((row & 7) << 3);
  }
  int vwofs[2];
#pragma unroll
  for (int i = 0; i < 2; i++) {
    int c = t + i * 256;                    // 8 chunks per 64-elem V^T row
    int d = c >> 3, part = c & 7;
    vwofs[i] = (d * 64 + part * 8) ^ ((d & 7) << 3);
  }
  // linear global source pointers (coalesced), bumped per kt
  const char* gK = (const char*)Kb + (size_t)ktBase * 24576 + (size_t)t * 16;
  const char* gV = (const char*)Vb + (size_t)(t >> 3) * 4096 + (size_t)(t & 7) * 16
                   + (size_t)ktBase * 128;

  v4u kreg[6], vreg[2];
  // prologue: stage tile 0 into buf0, then preload tile 1 into regs
#pragma unroll
  for (int i = 0; i < 6; i++) kreg[i] = *(const v4u*)(gK + i * 4096);
#pragma unroll
  for (int i = 0; i < 2; i++) vreg[i] = *(const v4u*)(gV + i * 131072);
#pragma unroll
  for (int i = 0; i < 6; i++) *(v4u*)&Ks[0][kwofs[i]] = kreg[i];
#pragma unroll
  for (int i = 0; i < 2; i++) *(v4u*)&Vs[0][vwofs[i]] = vreg[i];
  gK += 24576; gV += 128;
#pragma unroll
  for (int i = 0; i < 6; i++) kreg[i] = *(const v4u*)(gK + i * 4096);
#pragma unroll
  for (int i = 0; i < 2; i++) vreg[i] = *(const v4u*)(gV + i * 131072);

  // Q B-frags, resident: lane holds Q[qw0+lq][ks*16 + hi*8 .. +7]
  v8bf qf[12];
#pragma unroll
  for (int ks = 0; ks < 12; ++ks)
    qf[ks] = *(const v8bf*)(Qb + (size_t)(qw0 + lq) * 192 + ks * 16 + hi * 8);

  f32x16 o0 = {}, o1 = {};
  float mrun = -1e30f, lsum = 0.f;
  const int sx = (l & 7) << 3;              // read swizzle: rows are lq / lq+32 / d
  __syncthreads();

  for (int kt = 0; kt < NKT; ++kt) {
    const unsigned short* ksb = &Ks[kt & 1][0];
    const unsigned short* vsb = &Vs[kt & 1][0];
    unsigned short* ksw = &Ks[(kt & 1) ^ 1][0];
    unsigned short* vsw = &Vs[(kt & 1) ^ 1][0];

    // S^T = K Q^T : s0 = keys 0-31, s1 = keys 32-63 (cols = q)
    f32x16 s0 = {}, s1 = {};
    __builtin_amdgcn_s_setprio(1);
#pragma unroll
    for (int ks = 0; ks < 12; ++ks) {
      v8bf ka = *(const v8bf*)&ksb[((lq) * 192 + ks * 16 + hi * 8) ^ sx];
      v8bf kb = *(const v8bf*)&ksb[((lq + 32) * 192 + ks * 16 + hi * 8) ^ sx];
      s0 = __builtin_amdgcn_mfma_f32_32x32x16_bf16(ka, qf[ks], s0, 0, 0, 0);
      s1 = __builtin_amdgcn_mfma_f32_32x32x16_bf16(kb, qf[ks], s1, 0, 0, 0);
    }
    __builtin_amdgcn_s_setprio(0);

    // stage tile kt+1 into the OTHER buffer (overlaps with compute; readers
    // are on buf[kt&1], writers on buf[kt&1^1] -> no barrier needed here)
    if (kt < NKT - 1) {
#pragma unroll
      for (int i = 0; i < 6; i++) *(v4u*)&ksw[kwofs[i]] = kreg[i];
#pragma unroll
      for (int i = 0; i < 2; i++) *(v4u*)&vsw[vwofs[i]] = vreg[i];
    }
    // issue loads for tile kt+2 (ds_write above consumed the old reg values)
    if (kt < NKT - 2) {
      gK += 24576; gV += 128;
#pragma unroll
      for (int i = 0; i < 6; i++) kreg[i] = *(const v4u*)(gK + i * 4096);
#pragma unroll
      for (int i = 0; i < 2; i++) vreg[i] = *(const v4u*)(gV + i * 131072);
    }

    // ---- lane-local softmax over 32 values + one half-swap ----
    float tm[16];
#pragma unroll
    for (int i = 0; i < 16; i++) tm[i] = fmaxf(s0[i], s1[i]);
#pragma unroll
    for (int i = 0; i < 8; i++) tm[i] = fmaxf(tm[i], tm[i + 8]);
#pragma unroll
    for (int i = 0; i < 4; i++) tm[i] = fmaxf(tm[i], tm[i + 4]);
    float pmax = fmaxf(fmaxf(tm[0], tm[1]), fmaxf(tm[2], tm[3]));
    {
      v2u r = __builtin_amdgcn_permlane32_swap(__float_as_uint(pmax),
                                               __float_as_uint(pmax), false, false);
      pmax = fmaxf(__uint_as_float(r.x), __uint_as_float(r.y));
    }

    // T13 defer-max (THR=8)
    if (__any(pmax > mrun + 8.f)) {
      float mnew = fmaxf(mrun, pmax);
      float a = __builtin_exp2f((mrun - mnew) * LOG2E);
      mrun = mnew;
      lsum *= a;
      if (!hi) Al[w][lq] = a;
      asm volatile("s_waitcnt lgkmcnt(0)" ::: "memory");
#pragma unroll
      for (int r = 0; r < 16; r++) {
        float ar = Al[w][(r & 3) + 8 * (r >> 2) + 4 * hi];
        o0[r] *= ar; o1[r] *= ar;
      }
    }

    // P = exp(S - m), accumulate row-sum, build PV A-frags in-register
    const float mL = mrun * LOG2E;
    float p2[16];
    float ps = 0.f;
    uint32_t paw[4][4];                      // [ks][word]
    // s0 -> keys 0-31 -> PV ks=0,1
#pragma unroll
    for (int i = 0; i < 16; i++) { p2[i] = __builtin_exp2f(s0[i] * LOG2E - mL); ps += p2[i]; }
    {
      v2u r0 = __builtin_amdgcn_permlane32_swap(pk2(p2[0], p2[1]), pk2(p2[4], p2[5]), false, false);
      v2u r1 = __builtin_amdgcn_permlane32_swap(pk2(p2[2], p2[3]), pk2(p2[6], p2[7]), false, false);
      paw[0][0] = r0.x; paw[0][2] = r0.y; paw[0][1] = r1.x; paw[0][3] = r1.y;
      v2u r2 = __builtin_amdgcn_permlane32_swap(pk2(p2[8], p2[9]), pk2(p2[12], p2[13]), false, false);
      v2u r3 = __builtin_amdgcn_permlane32_swap(pk2(p2[10], p2[11]), pk2(p2[14], p2[15]), false, false);
      paw[1][0] = r2.x; paw[1][2] = r2.y; paw[1][1] = r3.x; paw[1][3] = r3.y;
    }
    // s1 -> keys 32-63 -> PV ks=2,3
#pragma unroll
    for (int i = 0; i < 16; i++) { p2[i] = __builtin_exp2f(s1[i] * LOG2E - mL); ps += p2[i]; }
    {
      v2u r0 = __builtin_amdgcn_permlane32_swap(pk2(p2[0], p2[1]), pk2(p2[4], p2[5]), false, false);
      v2u r1 = __builtin_amdgcn_permlane32_swap(pk2(p2[2], p2[3]), pk2(p2[6], p2[7]), false, false);
      paw[2][0] = r0.x; paw[2][2] = r0.y; paw[2][1] = r1.x; paw[2][3] = r1.y;
      v2u r2 = __builtin_amdgcn_permlane32_swap(pk2(p2[8], p2[9]), pk2(p2[12], p2[13]), false, false);
      v2u r3 = __builtin_amdgcn_permlane32_swap(pk2(p2[10], p2[11]), pk2(p2[14], p2[15]), false, false);
      paw[3][0] = r2.x; paw[3][2] = r2.y; paw[3][1] = r3.x; paw[3][3] = r3.y;
    }
    {
      v2u r = __builtin_amdgcn_permlane32_swap(__float_as_uint(ps),
                                               __float_as_uint(ps), false, false);
      lsum += __uint_as_float(r.x) + __uint_as_float(r.y);
    }

    // O += P V  (B-frags from Vs rows = d, contiguous along keys)
    __builtin_amdgcn_s_setprio(1);
#pragma unroll
    for (int ks = 0; ks < 4; ++ks) {
      union { uint32_t u[4]; v8bf v; } pa;
      pa.u[0] = paw[ks][0]; pa.u[1] = paw[ks][1];
      pa.u[2] = paw[ks][2]; pa.u[3] = paw[ks][3];
      v8bf v0 = *(const v8bf*)&vsb[((lq) * 64 + ks * 16 + hi * 8) ^ sx];
      v8bf v1 = *(const v8bf*)&vsb[((lq + 32) * 64 + ks * 16 + hi * 8) ^ sx];
      o0 = __builtin_amdgcn_mfma_f32_32x32x16_bf16(pa.v, v0, o0, 0, 0, 0);
      o1 = __builtin_amdgcn_mfma_f32_32x32x16_bf16(pa.v, v1, o1, 0, 0, 0);
    }
    __builtin_amdgcn_s_setprio(0);
    if (kt < NKT - 1) __syncthreads();      // buf[kt+1] writes visible; readers done
  }

  // epilogue: partial (unnormalized) O + (m,l) per q-row
  const size_t S = (size_t)24 * 2048;
  const size_t srow = (size_t)zsplit * S + (size_t)bh * 2048;
  if (!hi) {
    Ml[(srow + qw0 + lq) * 2]     = mrun;
    Ml[(srow + qw0 + lq) * 2 + 1] = lsum;
  }
#pragma unroll
  for (int r = 0; r < 16; r++) {
    const int q = qw0 + (r & 3) + 8 * (r >> 2) + 4 * hi;
    Op[(srow + q) * 64 + lq]      = o0[r];
    Op[(srow + q) * 64 + 32 + lq] = o1[r];
  }
}

// ---------- combine the two split-K partials ----------
__global__ __launch_bounds__(256) void attn_combine(
    const float* __restrict__ Op, const float* __restrict__ Ml,
    __bf16* __restrict__ Oe) {
  const size_t S = (size_t)24 * 2048;
  int row = blockIdx.x * 4 + (threadIdx.x >> 6);   // bh*2048 + q, 0..49151
  int lane = threadIdx.x & 63;
  int bh = row >> 11, q = row & 2047;
  int b = bh / 12, h = bh - b * 12;
  float m1 = Ml[(size_t)row * 2], l1 = Ml[(size_t)row * 2 + 1];
  float m2 = Ml[(S + row) * 2],   l2 = Ml[(S + row) * 2 + 1];
  float M = fmaxf(m1, m2);
  float a1 = __builtin_exp2f((m1 - M) * LOG2E);
  float a2 = __builtin_exp2f((m2 - M) * LOG2E);
  float rinv = 1.0f / (l1 * a1 + l2 * a2);
  float o1 = Op[(size_t)row * 64 + lane];
  float o2 = Op[S * 64 + (size_t)row * 64 + lane];
  Oe[((size_t)(b * 2048 + q)) * 768 + h * 64 + lane] = (__bf16)((o1 * a1 + o2 * a2) * rinv);
}

// ---------- launcher ----------
extern "C" void kernel_launch(void* const* d_in, const int* in_sizes, int n_in,
                              void* d_out, int out_size, void* d_ws, size_t ws_size,
                              hipStream_t stream) {
  const float* x    = (const float*)d_in[0];
  const float* Wqkv = (const float*)d_in[1];
  const float* bqkv = (const float*)d_in[2];
  const float* Wout = (const float*)d_in[3];
  const float* bout = (const float*)d_in[4];
  float* out = (float*)d_out;
  char* ws = (char*)d_ws;

  unsigned short* Acat  = (unsigned short*)(ws + 0);          // 18.9 MB (dead after gemm_qkv)
  unsigned short* BcatT = (unsigned short*)(ws + 18874368);   // 10.6 MB (dead after gemm_qkv)
  float*          QKV   = (float*)(ws + 29491200);            // 37.7 MB (dead after split_qkv)
  unsigned short* Qcat  = (unsigned short*)(ws + 67239936);   // 18.9 MB
  unsigned short* Kcat  = (unsigned short*)(ws + 86114304);   // 18.9 MB
  unsigned short* VT    = (unsigned short*)(ws + 104988672);  //  6.3 MB
  unsigned short* Oemb  = (unsigned short*)(ws + 111280128);  //  6.3 MB
  unsigned short* WoutT = (unsigned short*)(ws + 117571584);  //  1.2 MB
  // split-K partials alias the dead Acat/BcatT/QKV region:
  float*          Opart = (float*)(ws + 0);                   // 2 x 12.58 MB = 25.2 MB
  float*          Mlpart= (float*)(ws + 50331648);            //  0.8 MB

  prep_a   <<<dim3(3, 4096), 256, 0, stream>>>(x, Acat);
  prep_bqkv<<<dim3(3, 2304), 256, 0, stream>>>(Wqkv, BcatT);
  prep_wout<<<dim3(3, 768),  256, 0, stream>>>(Wout, WoutT);
  gemm_bf16_128<<<dim3(18 * 32), 256, 0, stream>>>(Acat, BcatT, bqkv, QKV, 4096, 2304, 2304);
  split_qkv<<<dim3(9, 4096), 256, 0, stream>>>(QKV, Qcat, Kcat, VT);
  attn<<<dim3(768), 256, 0, stream>>>(Qcat, Kcat, VT, Opart, Mlpart);
  attn_combine<<<dim3(12288), 256, 0, stream>>>(Opart, Mlpart, (__bf16*)Oemb);
  gemm_bf16_128<<<dim3(6 * 32), 256, 0, stream>>>(Oemb, WoutT, bout, out, 4096, 768, 768);
}

// Round 8
// 232.089 us; speedup vs baseline: 1.1986x; 1.1237x over previous
//
#include <hip/hip_runtime.h>
#include <stdint.h>

#define LOG2E 1.44269504088896340736f

typedef __bf16 v8bf __attribute__((ext_vector_type(8)));
typedef float f32x4 __attribute__((ext_vector_type(4)));
typedef float f32x16 __attribute__((ext_vector_type(16)));
typedef unsigned int v4u __attribute__((ext_vector_type(4)));
typedef unsigned int v2u __attribute__((ext_vector_type(2)));

// ---------- helpers ----------
__device__ __forceinline__ unsigned short f2bf(float f) {
  union { float f; uint32_t u; } v; v.f = f;
  uint32_t u = v.u;
  uint32_t r = (u + 0x7FFFu + ((u >> 16) & 1u)) >> 16;   // RN-even
  return (unsigned short)r;
}
__device__ __forceinline__ float bf2f(unsigned short h) {
  union { uint32_t u; float f; } v; v.u = ((uint32_t)h) << 16;
  return v.f;
}
__device__ __forceinline__ void gll16(const void* g, void* l) {
  __builtin_amdgcn_global_load_lds(
      (const __attribute__((address_space(1))) unsigned int*)g,
      (__attribute__((address_space(3))) unsigned int*)l, 16, 0, 0);
}
__device__ __forceinline__ uint32_t pk2(float a, float b) {
  union { __bf16 h[2]; uint32_t u; } x;
  x.h[0] = (__bf16)a; x.h[1] = (__bf16)b;
  return x.u;
}

// ---------- prep: x -> [hi | lo | hi]  (4096 x 2304 bf16) ----------
__global__ void prep_a(const float* __restrict__ x, unsigned short* __restrict__ Acat) {
  int n = blockIdx.x * 256 + threadIdx.x;   // 0..767
  int m = blockIdx.y;                       // 0..4095
  float v = x[(size_t)m * 768 + n];
  unsigned short H = f2bf(v);
  unsigned short L = f2bf(v - bf2f(H));
  size_t base = (size_t)m * 2304;
  Acat[base + n] = H;
  Acat[base + 768 + n] = L;
  Acat[base + 1536 + n] = H;
}

// ---------- prep: Wqkv^T cat -> rows n: [Whi | Whi | Wlo] (2304 x 2304 bf16) ----------
__global__ void prep_bqkv(const float* __restrict__ W, unsigned short* __restrict__ BT) {
  int k = blockIdx.x * 256 + threadIdx.x;   // 0..767
  int n = blockIdx.y;                       // 0..2303
  float v = W[(size_t)k * 2304 + n];
  unsigned short H = f2bf(v);
  unsigned short L = f2bf(v - bf2f(H));
  size_t base = (size_t)n * 2304;
  BT[base + k] = H;
  BT[base + 768 + k] = H;
  BT[base + 1536 + k] = L;
}

// ---------- prep: Wout^T single bf16 (768 x 768) ----------
__global__ void prep_wout(const float* __restrict__ W, unsigned short* __restrict__ BT) {
  int k = blockIdx.x * 256 + threadIdx.x;   // 0..767
  int n = blockIdx.y;                       // 0..767
  BT[(size_t)n * 768 + k] = f2bf(W[(size_t)k * 768 + n]);
}

// ---------- GEMM: C[M,N] = A[M,K](bf16) * B^T[N,K](bf16) + bias[N], fp32 out ----------
// Flat grid = (N/128)*32 blocks, M fixed at 4096 (32 y-tiles).
// XCD swizzle (id%8 round-robin): ytile = (f&7)*4 + (slot&3), xtile = slot>>2
__global__ __launch_bounds__(256) void gemm_bf16_128(
    const unsigned short* __restrict__ A, const unsigned short* __restrict__ B,
    const float* __restrict__ bias, float* __restrict__ C,
    int M, int N, int K) {
  __shared__ unsigned short As[128 * 32];
  __shared__ unsigned short Bs[128 * 32];
  const int t = threadIdx.x;
  const int f = blockIdx.x, slot = f >> 3;
  const int m0 = ((f & 7) * 4 + (slot & 3)) * 128;
  const int n0 = (slot >> 2) * 128;
  const int w = t >> 6, l = t & 63;
  const int wm = (w >> 1) * 64, wn = (w & 1) * 64;
  const int lr = l & 15, lg = l >> 4;
  f32x4 acc[4][4] = {};
  const int nk = K >> 5;
  for (int kt = 0; kt < nk; ++kt) {
    const int k0 = kt << 5;
    {
      const int c0 = t, c1 = t + 256;
      gll16(A + (size_t)(m0 + (c0 >> 2)) * K + k0 + ((c0 & 3) << 3), &As[c0 * 8]);
      gll16(A + (size_t)(m0 + (c1 >> 2)) * K + k0 + ((c1 & 3) << 3), &As[c1 * 8]);
      gll16(B + (size_t)(n0 + (c0 >> 2)) * K + k0 + ((c0 & 3) << 3), &Bs[c0 * 8]);
      gll16(B + (size_t)(n0 + (c1 >> 2)) * K + k0 + ((c1 & 3) << 3), &Bs[c1 * 8]);
    }
    __syncthreads();
    v8bf a[4], b[4];
#pragma unroll
    for (int i = 0; i < 4; i++) {
      a[i] = *(const v8bf*)&As[(wm + i * 16 + lr) * 32 + lg * 8];
      b[i] = *(const v8bf*)&Bs[(wn + i * 16 + lr) * 32 + lg * 8];
    }
#pragma unroll
    for (int i = 0; i < 4; i++)
#pragma unroll
      for (int j = 0; j < 4; j++)
        acc[i][j] = __builtin_amdgcn_mfma_f32_16x16x32_bf16(a[i], b[j], acc[i][j], 0, 0, 0);
    __syncthreads();
  }
#pragma unroll
  for (int i = 0; i < 4; i++) {
#pragma unroll
    for (int j = 0; j < 4; j++) {
      const int col = n0 + wn + j * 16 + lr;
      const float bv = bias[col];
#pragma unroll
      for (int r = 0; r < 4; r++) {
        const int row = m0 + wm + i * 16 + lg * 4 + r;
        C[(size_t)row * N + col] = acc[i][j][r] + bv;
      }
    }
  }
}

// ---------- split qkv fp32 -> Qcat/Kcat (split-bf16, *8 folded into Q), V^T bf16 ----------
__global__ void split_qkv(const float* __restrict__ qkv,
                          unsigned short* __restrict__ Qc,
                          unsigned short* __restrict__ Kc,
                          unsigned short* __restrict__ VT) {
  int n = blockIdx.x * 256 + threadIdx.x;   // 0..2303
  int m = blockIdx.y;                       // 0..4095
  float val = qkv[(size_t)m * 2304 + n];
  int h = n / 192;
  int j = n - h * 192;
  int b = m >> 11, p = m & 2047;
  int bh = b * 12 + h;
  size_t base = (size_t)bh * 2048 * 192 + (size_t)p * 192;
  if (j < 64) {
    float v8v = val * 8.0f;                 // fold logits *= sqrt(64) (exact: pow2)
    unsigned short H = f2bf(v8v);
    unsigned short L = f2bf(v8v - bf2f(H));
    Qc[base + j] = H; Qc[base + 64 + j] = L; Qc[base + 128 + j] = H;
  } else if (j < 128) {
    int d = j - 64;
    unsigned short H = f2bf(val);
    unsigned short L = f2bf(val - bf2f(H));
    Kc[base + d] = H; Kc[base + 64 + d] = H; Kc[base + 128 + d] = L;
  } else {
    int d = j - 128;
    VT[(size_t)bh * 64 * 2048 + (size_t)d * 2048 + p] = f2bf(val);
  }
}

// ---------- flash attention: KVBLK=32, lean registers, 3 blocks/CU ----------
// Flat grid 768 = 8 xcd x 6 pairGroups x 16 q-tiles; split-K x2 (32 kt of 32 keys).
// Register diet: single f32x16 s (not s0+s1), exp in-place into s, paw[2],
// kreg[3]+vreg[1] -> total regs (arch+ACC) fits 3 waves/SIMD (launch_bounds 256,3).
// LDS 32.5KB dbuf -> 3 blocks/CU co-resident with grid 768 = exactly 3/CU.
// K swizzle ^(row&7)<<3 (192-elem rows); V swizzle ^(d&3)<<3 (32-elem rows).
__global__ __launch_bounds__(256, 3) void attn(
    const unsigned short* __restrict__ Qc, const unsigned short* __restrict__ Kc,
    const unsigned short* __restrict__ VT,
    float* __restrict__ Op, float* __restrict__ Ml) {
  __shared__ __align__(16) unsigned short Ks[2][32 * 192];
  __shared__ __align__(16) unsigned short Vs[2][64 * 32];
  __shared__ float Al[4][32];
  const int t = threadIdx.x, w = t >> 6, l = t & 63;
  const int lq = l & 31, hi = l >> 5;
  const int f = blockIdx.x;
  const int xcd = f & 7, slot = f >> 3;
  const int p = xcd + 8 * (slot >> 4);      // 0..47: (bh,split) pair
  const int bh = p >> 1, zsplit = p & 1;
  const int q0 = (slot & 15) * 128;
  const int qw0 = q0 + w * 32;
  const int NKT = 32;
  const int ktBase = zsplit * 32;           // 32 key-tiles of 32 keys per split
  const unsigned short* Qb = Qc + (size_t)bh * 2048 * 192;
  const unsigned short* Kb = Kc + (size_t)bh * 2048 * 192;
  const unsigned short* Vb = VT + (size_t)bh * 64 * 2048;

  // hoisted swizzled LDS write offsets (element units)
  int kwofs[3];
#pragma unroll
  for (int i = 0; i < 3; i++) {
    int c = t + i * 256;                    // 16B chunk; 24 chunks per 192-elem row
    int row = c / 24, cc = c - row * 24;
    kwofs[i] = (row * 192 + cc * 8) ^ ((row & 7) << 3);
  }
  const int vd = t >> 2, vpart = t & 3;     // 4 chunks per 32-elem V row
  const int vwofs = (vd * 32 + vpart * 8) ^ ((vd & 3) << 3);

  // linear global source pointers (coalesced), bumped per kt
  const char* gK = (const char*)Kb + (size_t)ktBase * 12288 + (size_t)t * 16;
  const char* gV = (const char*)Vb + (size_t)vd * 4096 + (size_t)vpart * 16
                   + (size_t)ktBase * 64;

  v4u kreg[3], vreg;
  // prologue: stage tile 0 into buf0, preload tile 1 into regs
#pragma unroll
  for (int i = 0; i < 3; i++) kreg[i] = *(const v4u*)(gK + i * 4096);
  vreg = *(const v4u*)gV;
#pragma unroll
  for (int i = 0; i < 3; i++) *(v4u*)&Ks[0][kwofs[i]] = kreg[i];
  *(v4u*)&Vs[0][vwofs] = vreg;
  gK += 12288; gV += 64;
#pragma unroll
  for (int i = 0; i < 3; i++) kreg[i] = *(const v4u*)(gK + i * 4096);
  vreg = *(const v4u*)gV;

  // Q B-frags, resident: lane holds Q[qw0+lq][ks*16 + hi*8 .. +7]
  v8bf qf[12];
#pragma unroll
  for (int ks = 0; ks < 12; ++ks)
    qf[ks] = *(const v8bf*)(Qb + (size_t)(qw0 + lq) * 192 + ks * 16 + hi * 8);

  f32x16 o0 = {}, o1 = {};
  float mrun = -1e30f, lsum = 0.f;
  const int sxk = (lq & 7) << 3;            // K read swizzle (rows = lq)
  const int sxv = (lq & 3) << 3;            // V read swizzle (rows = lq, lq+32)
  __syncthreads();

  for (int kt = 0; kt < NKT; ++kt) {
    const unsigned short* ksb = &Ks[kt & 1][0];
    const unsigned short* vsb = &Vs[kt & 1][0];
    unsigned short* ksw = &Ks[(kt & 1) ^ 1][0];
    unsigned short* vsw = &Vs[(kt & 1) ^ 1][0];

    // S^T = K Q^T : keys 0-31 of this tile in one C-frag (cols = q)
    f32x16 s = {};
    __builtin_amdgcn_s_setprio(1);
#pragma unroll
    for (int ks = 0; ks < 12; ++ks) {
      v8bf ka = *(const v8bf*)&ksb[(lq * 192 + ks * 16 + hi * 8) ^ sxk];
      s = __builtin_amdgcn_mfma_f32_32x32x16_bf16(ka, qf[ks], s, 0, 0, 0);
    }
    __builtin_amdgcn_s_setprio(0);

    // stage tile kt+1 into the OTHER buffer (overlaps with this tile's compute)
    if (kt < NKT - 1) {
#pragma unroll
      for (int i = 0; i < 3; i++) *(v4u*)&ksw[kwofs[i]] = kreg[i];
      *(v4u*)&vsw[vwofs] = vreg;
    }
    // issue loads for tile kt+2
    if (kt < NKT - 2) {
      gK += 12288; gV += 64;
#pragma unroll
      for (int i = 0; i < 3; i++) kreg[i] = *(const v4u*)(gK + i * 4096);
      vreg = *(const v4u*)gV;
    }

    // ---- lane-local softmax (tree) + one half-swap ----
    float tm[8];
#pragma unroll
    for (int i = 0; i < 8; i++) tm[i] = fmaxf(s[i], s[i + 8]);
#pragma unroll
    for (int i = 0; i < 4; i++) tm[i] = fmaxf(tm[i], tm[i + 4]);
    float pmax = fmaxf(fmaxf(tm[0], tm[1]), fmaxf(tm[2], tm[3]));
    {
      v2u r = __builtin_amdgcn_permlane32_swap(__float_as_uint(pmax),
                                               __float_as_uint(pmax), false, false);
      pmax = fmaxf(__uint_as_float(r.x), __uint_as_float(r.y));
    }

    // T13 defer-max, THR=24 (P <= e^24, safe in bf16/f32; rescale is rare)
    if (__any(pmax > mrun + 24.f)) {
      float mnew = fmaxf(mrun, pmax);
      float a = __builtin_exp2f((mrun - mnew) * LOG2E);
      mrun = mnew;
      lsum *= a;
      if (!hi) Al[w][lq] = a;
#pragma unroll
      for (int r = 0; r < 16; r++) {
        float ar = Al[w][(r & 3) + 8 * (r >> 2) + 4 * hi];
        o0[r] *= ar; o1[r] *= ar;
      }
    }

    // P = exp(S - m) in-place, tree row-sum, pack PV A-frags in-register
    const float mL = mrun * LOG2E;
#pragma unroll
    for (int i = 0; i < 16; i++) s[i] = __builtin_exp2f(s[i] * LOG2E - mL);
    {
      float a0 = (s[0] + s[8]) + (s[1] + s[9]);
      float a1 = (s[2] + s[10]) + (s[3] + s[11]);
      float a2 = (s[4] + s[12]) + (s[5] + s[13]);
      float a3 = (s[6] + s[14]) + (s[7] + s[15]);
      float ps = (a0 + a1) + (a2 + a3);
      v2u r = __builtin_amdgcn_permlane32_swap(__float_as_uint(ps),
                                               __float_as_uint(ps), false, false);
      lsum += __uint_as_float(r.x) + __uint_as_float(r.y);
    }
    uint32_t paw[2][4];
    {
      v2u r0 = __builtin_amdgcn_permlane32_swap(pk2(s[0], s[1]), pk2(s[4], s[5]), false, false);
      v2u r1 = __builtin_amdgcn_permlane32_swap(pk2(s[2], s[3]), pk2(s[6], s[7]), false, false);
      paw[0][0] = r0.x; paw[0][2] = r0.y; paw[0][1] = r1.x; paw[0][3] = r1.y;
      v2u r2 = __builtin_amdgcn_permlane32_swap(pk2(s[8], s[9]), pk2(s[12], s[13]), false, false);
      v2u r3 = __builtin_amdgcn_permlane32_swap(pk2(s[10], s[11]), pk2(s[14], s[15]), false, false);
      paw[1][0] = r2.x; paw[1][2] = r2.y; paw[1][1] = r3.x; paw[1][3] = r3.y;
    }

    // O += P V  (V^T rows = d; 32-key tile -> 2 A-frags)
    __builtin_amdgcn_s_setprio(1);
#pragma unroll
    for (int ks = 0; ks < 2; ++ks) {
      union { uint32_t u[4]; v8bf v; } pa;
      pa.u[0] = paw[ks][0]; pa.u[1] = paw[ks][1];
      pa.u[2] = paw[ks][2]; pa.u[3] = paw[ks][3];
      v8bf v0 = *(const v8bf*)&vsb[(lq * 32 + ks * 16 + hi * 8) ^ sxv];
      v8bf v1 = *(const v8bf*)&vsb[((lq + 32) * 32 + ks * 16 + hi * 8) ^ sxv];
      o0 = __builtin_amdgcn_mfma_f32_32x32x16_bf16(pa.v, v0, o0, 0, 0, 0);
      o1 = __builtin_amdgcn_mfma_f32_32x32x16_bf16(pa.v, v1, o1, 0, 0, 0);
    }
    __builtin_amdgcn_s_setprio(0);
    if (kt < NKT - 1) __syncthreads();
  }

  // epilogue: partial (unnormalized) O + (m,l) per q-row
  const size_t S = (size_t)24 * 2048;
  const size_t srow = (size_t)zsplit * S + (size_t)bh * 2048;
  if (!hi) {
    Ml[(srow + qw0 + lq) * 2]     = mrun;
    Ml[(srow + qw0 + lq) * 2 + 1] = lsum;
  }
#pragma unroll
  for (int r = 0; r < 16; r++) {
    const int q = qw0 + (r & 3) + 8 * (r >> 2) + 4 * hi;
    Op[(srow + q) * 64 + lq]      = o0[r];
    Op[(srow + q) * 64 + 32 + lq] = o1[r];
  }
}

// ---------- combine the two split-K partials ----------
__global__ __launch_bounds__(256) void attn_combine(
    const float* __restrict__ Op, const float* __restrict__ Ml,
    __bf16* __restrict__ Oe) {
  const size_t S = (size_t)24 * 2048;
  int row = blockIdx.x * 4 + (threadIdx.x >> 6);   // bh*2048 + q, 0..49151
  int lane = threadIdx.x & 63;
  int bh = row >> 11, q = row & 2047;
  int b = bh / 12, h = bh - b * 12;
  float m1 = Ml[(size_t)row * 2], l1 = Ml[(size_t)row * 2 + 1];
  float m2 = Ml[(S + row) * 2],   l2 = Ml[(S + row) * 2 + 1];
  float M = fmaxf(m1, m2);
  float a1 = __builtin_exp2f((m1 - M) * LOG2E);
  float a2 = __builtin_exp2f((m2 - M) * LOG2E);
  float rinv = 1.0f / (l1 * a1 + l2 * a2);
  float o1 = Op[(size_t)row * 64 + lane];
  float o2 = Op[S * 64 + (size_t)row * 64 + lane];
  Oe[((size_t)(b * 2048 + q)) * 768 + h * 64 + lane] = (__bf16)((o1 * a1 + o2 * a2) * rinv);
}

// ---------- launcher ----------
extern "C" void kernel_launch(void* const* d_in, const int* in_sizes, int n_in,
                              void* d_out, int out_size, void* d_ws, size_t ws_size,
                              hipStream_t stream) {
  const float* x    = (const float*)d_in[0];
  const float* Wqkv = (const float*)d_in[1];
  const float* bqkv = (const float*)d_in[2];
  const float* Wout = (const float*)d_in[3];
  const float* bout = (const float*)d_in[4];
  float* out = (float*)d_out;
  char* ws = (char*)d_ws;

  unsigned short* Acat  = (unsigned short*)(ws + 0);          // 18.9 MB (dead after gemm_qkv)
  unsigned short* BcatT = (unsigned short*)(ws + 18874368);   // 10.6 MB (dead after gemm_qkv)
  float*          QKV   = (float*)(ws + 29491200);            // 37.7 MB (dead after split_qkv)
  unsigned short* Qcat  = (unsigned short*)(ws + 67239936);   // 18.9 MB
  unsigned short* Kcat  = (unsigned short*)(ws + 86114304);   // 18.9 MB
  unsigned short* VT    = (unsigned short*)(ws + 104988672);  //  6.3 MB
  unsigned short* Oemb  = (unsigned short*)(ws + 111280128);  //  6.3 MB
  unsigned short* WoutT = (unsigned short*)(ws + 117571584);  //  1.2 MB
  // split-K partials alias the dead Acat/BcatT/QKV region:
  float*          Opart = (float*)(ws + 0);                   // 2 x 12.58 MB = 25.2 MB
  float*          Mlpart= (float*)(ws + 50331648);            //  0.8 MB

  prep_a   <<<dim3(3, 4096), 256, 0, stream>>>(x, Acat);
  prep_bqkv<<<dim3(3, 2304), 256, 0, stream>>>(Wqkv, BcatT);
  prep_wout<<<dim3(3, 768),  256, 0, stream>>>(Wout, WoutT);
  gemm_bf16_128<<<dim3(18 * 32), 256, 0, stream>>>(Acat, BcatT, bqkv, QKV, 4096, 2304, 2304);
  split_qkv<<<dim3(9, 4096), 256, 0, stream>>>(QKV, Qcat, Kcat, VT);
  attn<<<dim3(768), 256, 0, stream>>>(Qcat, Kcat, VT, Opart, Mlpart);
  attn_combine<<<dim3(12288), 256, 0, stream>>>(Opart, Mlpart, (__bf16*)Oemb);
  gemm_bf16_128<<<dim3(6 * 32), 256, 0, stream>>>(Oemb, WoutT, bout, out, 4096, 768, 768);
}

// Round 10
// 214.875 us; speedup vs baseline: 1.2946x; 1.0801x over previous
//
#include <hip/hip_runtime.h>
#include <stdint.h>

#define LOG2E 1.44269504088896340736f

typedef __bf16 v8bf __attribute__((ext_vector_type(8)));
typedef float f32x4 __attribute__((ext_vector_type(4)));
typedef float f32x16 __attribute__((ext_vector_type(16)));
typedef unsigned int v4u __attribute__((ext_vector_type(4)));
typedef unsigned int v2u __attribute__((ext_vector_type(2)));

// ---------- helpers ----------
__device__ __forceinline__ unsigned short f2bf(float f) {
  union { float f; uint32_t u; } v; v.f = f;
  uint32_t u = v.u;
  uint32_t r = (u + 0x7FFFu + ((u >> 16) & 1u)) >> 16;   // RN-even
  return (unsigned short)r;
}
__device__ __forceinline__ float bf2f(unsigned short h) {
  union { uint32_t u; float f; } v; v.u = ((uint32_t)h) << 16;
  return v.f;
}
__device__ __forceinline__ void gll16(const void* g, void* l) {
  __builtin_amdgcn_global_load_lds(
      (const __attribute__((address_space(1))) unsigned int*)g,
      (__attribute__((address_space(3))) unsigned int*)l, 16, 0, 0);
}
__device__ __forceinline__ uint32_t pk2(float a, float b) {
  union { __bf16 h[2]; uint32_t u; } x;
  x.h[0] = (__bf16)a; x.h[1] = (__bf16)b;
  return x.u;
}

// Permuted QKV column order c' (GEMM output):
//   c' in [0,1536): head h = c'>>7, j = c'&127  -> orig col n = h*192 + j   (q|k, TRIPLED path)
//   c' in [1536,2304): h = (c'-1536)>>6, d = (c'-1536)&63 -> n = h*192+128+d (v, plain path)

// ---------- fused prep: Acat, BcatT (qk rows, permuted), WvT (v rows), WoT, bperm ----------
__global__ void prep_fused(const float* __restrict__ x, const float* __restrict__ Wqkv,
                           const float* __restrict__ Wout, const float* __restrict__ bqkv,
                           unsigned short* __restrict__ Acat,
                           unsigned short* __restrict__ BcatT,
                           unsigned short* __restrict__ WvT,
                           unsigned short* __restrict__ WoT,
                           float* __restrict__ bperm) {
  const int t = threadIdx.x, f = blockIdx.x;
  if (f < 12288) {                    // Acat: x -> [hi | lo | hi]
    int m = f / 3, n = (f - m * 3) * 256 + t;
    float v = x[(size_t)m * 768 + n];
    unsigned short H = f2bf(v);
    unsigned short L = f2bf(v - bf2f(H));
    size_t base = (size_t)m * 2304;
    Acat[base + n] = H;
    Acat[base + 768 + n] = L;
    Acat[base + 1536 + n] = H;
  } else if (f < 19200) {             // Wqkv columns, permuted row order
    int g = f - 12288;
    int cp = g / 3, k = (g - cp * 3) * 256 + t;   // cp = c' (permuted), k = input dim
    int n;                                         // original Wqkv column
    if (cp < 1536) n = (cp >> 7) * 192 + (cp & 127);
    else           n = ((cp - 1536) >> 6) * 192 + 128 + ((cp - 1536) & 63);
    float v = Wqkv[(size_t)k * 2304 + n];
    unsigned short H = f2bf(v);
    if (cp < 1536) {
      unsigned short L = f2bf(v - bf2f(H));
      size_t base = (size_t)cp * 2304;
      BcatT[base + k] = H;
      BcatT[base + 768 + k] = H;
      BcatT[base + 1536 + k] = L;
    } else {
      WvT[(size_t)(cp - 1536) * 768 + k] = H;
    }
  } else if (f < 21504) {             // Wout^T plain bf16
    int g = f - 19200;
    int n = g / 3, k = (g - n * 3) * 256 + t;
    WoT[(size_t)n * 768 + k] = f2bf(Wout[(size_t)k * 768 + n]);
  } else {                            // permuted bias (2304 f32)
    int i = (f - 21504) * 256 + t;    // i = c'
    int n;
    if (i < 1536) n = (i >> 7) * 192 + (i & 127);
    else          n = ((i - 1536) >> 6) * 192 + 128 + ((i - 1536) & 63);
    bperm[i] = bqkv[n];
  }
}

// ---------- fused QKV GEMM: tripled K=2304 for c'<1536 (q,k), plain K=768 for v ----------
// Flat grid 576 = 8 xcd x 72; m0 = ((f&7)*4 + (slot&3))*128, xt = slot>>2 (0..17).
__global__ __launch_bounds__(256) void gemm_qkv(
    const unsigned short* __restrict__ Acat, const unsigned short* __restrict__ BcatT,
    const unsigned short* __restrict__ WvT, const float* __restrict__ bperm,
    float* __restrict__ C) {
  __shared__ unsigned short As[128 * 32];
  __shared__ unsigned short Bs[128 * 32];
  const int t = threadIdx.x;
  const int f = blockIdx.x, slot = f >> 3;
  const int m0 = ((f & 7) * 4 + (slot & 3)) * 128;
  const int xt = slot >> 2;
  const bool trip = xt < 12;
  const int n0 = xt * 128;
  const unsigned short* Bp = trip ? BcatT + (size_t)n0 * 2304
                                  : WvT + (size_t)(n0 - 1536) * 768;
  const int sB = trip ? 2304 : 768;
  const int nk = trip ? 72 : 24;
  const int w = t >> 6, l = t & 63;
  const int wm = (w >> 1) * 64, wn = (w & 1) * 64;
  const int lr = l & 15, lg = l >> 4;
  f32x4 acc[4][4] = {};
  for (int kt = 0; kt < nk; ++kt) {
    const int k0 = kt << 5;
    {
      const int c0 = t, c1 = t + 256;
      gll16(Acat + (size_t)(m0 + (c0 >> 2)) * 2304 + k0 + ((c0 & 3) << 3), &As[c0 * 8]);
      gll16(Acat + (size_t)(m0 + (c1 >> 2)) * 2304 + k0 + ((c1 & 3) << 3), &As[c1 * 8]);
      gll16(Bp + (size_t)(c0 >> 2) * sB + k0 + ((c0 & 3) << 3), &Bs[c0 * 8]);
      gll16(Bp + (size_t)(c1 >> 2) * sB + k0 + ((c1 & 3) << 3), &Bs[c1 * 8]);
    }
    __syncthreads();
    v8bf a[4], b[4];
#pragma unroll
    for (int i = 0; i < 4; i++) {
      a[i] = *(const v8bf*)&As[(wm + i * 16 + lr) * 32 + lg * 8];
      b[i] = *(const v8bf*)&Bs[(wn + i * 16 + lr) * 32 + lg * 8];
    }
#pragma unroll
    for (int i = 0; i < 4; i++)
#pragma unroll
      for (int j = 0; j < 4; j++)
        acc[i][j] = __builtin_amdgcn_mfma_f32_16x16x32_bf16(a[i], b[j], acc[i][j], 0, 0, 0);
    __syncthreads();
  }
#pragma unroll
  for (int i = 0; i < 4; i++) {
#pragma unroll
    for (int j = 0; j < 4; j++) {
      const int col = n0 + wn + j * 16 + lr;
      const float bv = bperm[col];
#pragma unroll
      for (int r = 0; r < 4; r++) {
        const int row = m0 + wm + i * 16 + lg * 4 + r;
        C[(size_t)row * 2304 + col] = acc[i][j][r] + bv;
      }
    }
  }
}

// ---------- generic GEMM (out-proj): C[M,N] = A[M,K] * B^T[N,K] + bias ----------
__global__ __launch_bounds__(256) void gemm_bf16_128(
    const unsigned short* __restrict__ A, const unsigned short* __restrict__ B,
    const float* __restrict__ bias, float* __restrict__ C,
    int M, int N, int K) {
  __shared__ unsigned short As[128 * 32];
  __shared__ unsigned short Bs[128 * 32];
  const int t = threadIdx.x;
  const int f = blockIdx.x, slot = f >> 3;
  const int m0 = ((f & 7) * 4 + (slot & 3)) * 128;
  const int n0 = (slot >> 2) * 128;
  const int w = t >> 6, l = t & 63;
  const int wm = (w >> 1) * 64, wn = (w & 1) * 64;
  const int lr = l & 15, lg = l >> 4;
  f32x4 acc[4][4] = {};
  const int nk = K >> 5;
  for (int kt = 0; kt < nk; ++kt) {
    const int k0 = kt << 5;
    {
      const int c0 = t, c1 = t + 256;
      gll16(A + (size_t)(m0 + (c0 >> 2)) * K + k0 + ((c0 & 3) << 3), &As[c0 * 8]);
      gll16(A + (size_t)(m0 + (c1 >> 2)) * K + k0 + ((c1 & 3) << 3), &As[c1 * 8]);
      gll16(B + (size_t)(n0 + (c0 >> 2)) * K + k0 + ((c0 & 3) << 3), &Bs[c0 * 8]);
      gll16(B + (size_t)(n0 + (c1 >> 2)) * K + k0 + ((c1 & 3) << 3), &Bs[c1 * 8]);
    }
    __syncthreads();
    v8bf a[4], b[4];
#pragma unroll
    for (int i = 0; i < 4; i++) {
      a[i] = *(const v8bf*)&As[(wm + i * 16 + lr) * 32 + lg * 8];
      b[i] = *(const v8bf*)&Bs[(wn + i * 16 + lr) * 32 + lg * 8];
    }
#pragma unroll
    for (int i = 0; i < 4; i++)
#pragma unroll
      for (int j = 0; j < 4; j++)
        acc[i][j] = __builtin_amdgcn_mfma_f32_16x16x32_bf16(a[i], b[j], acc[i][j], 0, 0, 0);
    __syncthreads();
  }
#pragma unroll
  for (int i = 0; i < 4; i++) {
#pragma unroll
    for (int j = 0; j < 4; j++) {
      const int col = n0 + wn + j * 16 + lr;
      const float bv = bias[col];
#pragma unroll
      for (int r = 0; r < 4; r++) {
        const int row = m0 + wm + i * 16 + lg * 4 + r;
        C[(size_t)row * N + col] = acc[i][j][r] + bv;
      }
    }
  }
}

// ---------- split permuted qkv -> Qcat/Kcat (split-bf16, *8*log2e in Q), V^T bf16 ----------
// Input layout: QKV'[m][c'] with c' as defined above.
__global__ void split_qkv(const float* __restrict__ qkv,
                          unsigned short* __restrict__ Qc,
                          unsigned short* __restrict__ Kc,
                          unsigned short* __restrict__ VT) {
  int cp = blockIdx.x * 256 + threadIdx.x;  // 0..2303 (permuted col)
  int m = blockIdx.y;                       // 0..4095
  float val = qkv[(size_t)m * 2304 + cp];
  int b = m >> 11, p = m & 2047;
  if (cp < 1536) {
    int h = cp >> 7, j = cp & 127;
    int bh = b * 12 + h;
    size_t base = (size_t)bh * 2048 * 192 + (size_t)p * 192;
    if (j < 64) {
      // fold sqrt(64) AND log2e: softmax runs natively in log2 domain
      float v8v = val * (8.0f * LOG2E);
      unsigned short H = f2bf(v8v);
      unsigned short L = f2bf(v8v - bf2f(H));
      Qc[base + j] = H; Qc[base + 64 + j] = L; Qc[base + 128 + j] = H;
    } else {
      int d = j - 64;
      unsigned short H = f2bf(val);
      unsigned short L = f2bf(val - bf2f(H));
      Kc[base + d] = H; Kc[base + 64 + d] = H; Kc[base + 128 + d] = L;
    }
  } else {
    int h = (cp - 1536) >> 6, d = (cp - 1536) & 63;
    int bh = b * 12 + h;
    VT[(size_t)bh * 64 * 2048 + (size_t)d * 2048 + p] = f2bf(val);
  }
}

// ---------- flash attention: KVBLK=32, log2-domain softmax, 3 blocks/CU ----------
// Flat grid 768 = 8 xcd x 6 pairGroups x 16 q-tiles; split-K x2 (32 kt of 32 keys).
__global__ __launch_bounds__(256, 3) void attn(
    const unsigned short* __restrict__ Qc, const unsigned short* __restrict__ Kc,
    const unsigned short* __restrict__ VT,
    float* __restrict__ Op, float* __restrict__ Ml) {
  __shared__ __align__(16) unsigned short Ks[2][32 * 192];
  __shared__ __align__(16) unsigned short Vs[2][64 * 32];
  __shared__ float Al[4][32];
  const int t = threadIdx.x, w = t >> 6, l = t & 63;
  const int lq = l & 31, hi = l >> 5;
  const int f = blockIdx.x;
  const int xcd = f & 7, slot = f >> 3;
  const int p = xcd + 8 * (slot >> 4);      // 0..47: (bh,split) pair
  const int bh = p >> 1, zsplit = p & 1;
  const int q0 = (slot & 15) * 128;
  const int qw0 = q0 + w * 32;
  const int NKT = 32;
  const int ktBase = zsplit * 32;
  const unsigned short* Qb = Qc + (size_t)bh * 2048 * 192;
  const unsigned short* Kb = Kc + (size_t)bh * 2048 * 192;
  const unsigned short* Vb = VT + (size_t)bh * 64 * 2048;

  int kwofs[3];
#pragma unroll
  for (int i = 0; i < 3; i++) {
    int c = t + i * 256;
    int row = c / 24, cc = c - row * 24;
    kwofs[i] = (row * 192 + cc * 8) ^ ((row & 7) << 3);
  }
  const int vd = t >> 2, vpart = t & 3;
  const int vwofs = (vd * 32 + vpart * 8) ^ ((vd & 3) << 3);

  const char* gK = (const char*)Kb + (size_t)ktBase * 12288 + (size_t)t * 16;
  const char* gV = (const char*)Vb + (size_t)vd * 4096 + (size_t)vpart * 16
                   + (size_t)ktBase * 64;

  v4u kreg[3], vreg;
#pragma unroll
  for (int i = 0; i < 3; i++) kreg[i] = *(const v4u*)(gK + i * 4096);
  vreg = *(const v4u*)gV;
#pragma unroll
  for (int i = 0; i < 3; i++) *(v4u*)&Ks[0][kwofs[i]] = kreg[i];
  *(v4u*)&Vs[0][vwofs] = vreg;
  gK += 12288; gV += 64;
#pragma unroll
  for (int i = 0; i < 3; i++) kreg[i] = *(const v4u*)(gK + i * 4096);
  vreg = *(const v4u*)gV;

  v8bf qf[12];
#pragma unroll
  for (int ks = 0; ks < 12; ++ks)
    qf[ks] = *(const v8bf*)(Qb + (size_t)(qw0 + lq) * 192 + ks * 16 + hi * 8);

  f32x16 o0 = {}, o1 = {};
  float mrun = -1e30f, lsum = 0.f;
  const int sxk = (lq & 7) << 3;
  const int sxv = (lq & 3) << 3;
  __syncthreads();

  for (int kt = 0; kt < NKT; ++kt) {
    const unsigned short* ksb = &Ks[kt & 1][0];
    const unsigned short* vsb = &Vs[kt & 1][0];
    unsigned short* ksw = &Ks[(kt & 1) ^ 1][0];
    unsigned short* vsw = &Vs[(kt & 1) ^ 1][0];

    // S^T(log2) = K Q^T
    f32x16 s = {};
    __builtin_amdgcn_s_setprio(1);
#pragma unroll
    for (int ks = 0; ks < 12; ++ks) {
      v8bf ka = *(const v8bf*)&ksb[(lq * 192 + ks * 16 + hi * 8) ^ sxk];
      s = __builtin_amdgcn_mfma_f32_32x32x16_bf16(ka, qf[ks], s, 0, 0, 0);
    }
    __builtin_amdgcn_s_setprio(0);

    if (kt < NKT - 1) {
#pragma unroll
      for (int i = 0; i < 3; i++) *(v4u*)&ksw[kwofs[i]] = kreg[i];
      *(v4u*)&vsw[vwofs] = vreg;
    }
    if (kt < NKT - 2) {
      gK += 12288; gV += 64;
#pragma unroll
      for (int i = 0; i < 3; i++) kreg[i] = *(const v4u*)(gK + i * 4096);
      vreg = *(const v4u*)gV;
    }

    // lane-local max (tree) + one half-swap
    float tm[8];
#pragma unroll
    for (int i = 0; i < 8; i++) tm[i] = fmaxf(s[i], s[i + 8]);
#pragma unroll
    for (int i = 0; i < 4; i++) tm[i] = fmaxf(tm[i], tm[i + 4]);
    float pmax = fmaxf(fmaxf(tm[0], tm[1]), fmaxf(tm[2], tm[3]));
    {
      v2u r = __builtin_amdgcn_permlane32_swap(__float_as_uint(pmax),
                                               __float_as_uint(pmax), false, false);
      pmax = fmaxf(__uint_as_float(r.x), __uint_as_float(r.y));
    }

    // T13 defer-max, THR=32 (log2 units)
    if (__any(pmax > mrun + 32.f)) {
      float mnew = fmaxf(mrun, pmax);
      float a = __builtin_exp2f(mrun - mnew);
      mrun = mnew;
      lsum *= a;
      if (!hi) Al[w][lq] = a;
#pragma unroll
      for (int r = 0; r < 16; r++) {
        float ar = Al[w][(r & 3) + 8 * (r >> 2) + 4 * hi];
        o0[r] *= ar; o1[r] *= ar;
      }
    }

    // P = exp2(S - m) in-place, tree sum, pack PV A-frags
#pragma unroll
    for (int i = 0; i < 16; i++) s[i] = __builtin_exp2f(s[i] - mrun);
    {
      float a0 = (s[0] + s[8]) + (s[1] + s[9]);
      float a1 = (s[2] + s[10]) + (s[3] + s[11]);
      float a2 = (s[4] + s[12]) + (s[5] + s[13]);
      float a3 = (s[6] + s[14]) + (s[7] + s[15]);
      float ps = (a0 + a1) + (a2 + a3);
      v2u r = __builtin_amdgcn_permlane32_swap(__float_as_uint(ps),
                                               __float_as_uint(ps), false, false);
      lsum += __uint_as_float(r.x) + __uint_as_float(r.y);
    }
    uint32_t paw[2][4];
    {
      v2u r0 = __builtin_amdgcn_permlane32_swap(pk2(s[0], s[1]), pk2(s[4], s[5]), false, false);
      v2u r1 = __builtin_amdgcn_permlane32_swap(pk2(s[2], s[3]), pk2(s[6], s[7]), false, false);
      paw[0][0] = r0.x; paw[0][2] = r0.y; paw[0][1] = r1.x; paw[0][3] = r1.y;
      v2u r2 = __builtin_amdgcn_permlane32_swap(pk2(s[8], s[9]), pk2(s[12], s[13]), false, false);
      v2u r3 = __builtin_amdgcn_permlane32_swap(pk2(s[10], s[11]), pk2(s[14], s[15]), false, false);
      paw[1][0] = r2.x; paw[1][2] = r2.y; paw[1][1] = r3.x; paw[1][3] = r3.y;
    }

    // O += P V
    __builtin_amdgcn_s_setprio(1);
#pragma unroll
    for (int ks = 0; ks < 2; ++ks) {
      union { uint32_t u[4]; v8bf v; } pa;
      pa.u[0] = paw[ks][0]; pa.u[1] = paw[ks][1];
      pa.u[2] = paw[ks][2]; pa.u[3] = paw[ks][3];
      v8bf v0 = *(const v8bf*)&vsb[(lq * 32 + ks * 16 + hi * 8) ^ sxv];
      v8bf v1 = *(const v8bf*)&vsb[((lq + 32) * 32 + ks * 16 + hi * 8) ^ sxv];
      o0 = __builtin_amdgcn_mfma_f32_32x32x16_bf16(pa.v, v0, o0, 0, 0, 0);
      o1 = __builtin_amdgcn_mfma_f32_32x32x16_bf16(pa.v, v1, o1, 0, 0, 0);
    }
    __builtin_amdgcn_s_setprio(0);
    if (kt < NKT - 1) __syncthreads();
  }

  // epilogue: partial O + (m in log2 units, l)
  const size_t S = (size_t)24 * 2048;
  const size_t srow = (size_t)zsplit * S + (size_t)bh * 2048;
  if (!hi) {
    Ml[(srow + qw0 + lq) * 2]     = mrun;
    Ml[(srow + qw0 + lq) * 2 + 1] = lsum;
  }
#pragma unroll
  for (int r = 0; r < 16; r++) {
    const int q = qw0 + (r & 3) + 8 * (r >> 2) + 4 * hi;
    Op[(srow + q) * 64 + lq]      = o0[r];
    Op[(srow + q) * 64 + 32 + lq] = o1[r];
  }
}

// ---------- combine the two split-K partials (m in log2 units) ----------
__global__ __launch_bounds__(256) void attn_combine(
    const float* __restrict__ Op, const float* __restrict__ Ml,
    __bf16* __restrict__ Oe) {
  const size_t S = (size_t)24 * 2048;
  int row = blockIdx.x * 4 + (threadIdx.x >> 6);
  int lane = threadIdx.x & 63;
  int bh = row >> 11, q = row & 2047;
  int b = bh / 12, h = bh - b * 12;
  float m1 = Ml[(size_t)row * 2], l1 = Ml[(size_t)row * 2 + 1];
  float m2 = Ml[(S + row) * 2],   l2 = Ml[(S + row) * 2 + 1];
  float M = fmaxf(m1, m2);
  float a1 = __builtin_exp2f(m1 - M);
  float a2 = __builtin_exp2f(m2 - M);
  float rinv = 1.0f / (l1 * a1 + l2 * a2);
  float o1 = Op[(size_t)row * 64 + lane];
  float o2 = Op[S * 64 + (size_t)row * 64 + lane];
  Oe[((size_t)(b * 2048 + q)) * 768 + h * 64 + lane] = (__bf16)((o1 * a1 + o2 * a2) * rinv);
}

// ---------- launcher ----------
extern "C" void kernel_launch(void* const* d_in, const int* in_sizes, int n_in,
                              void* d_out, int out_size, void* d_ws, size_t ws_size,
                              hipStream_t stream) {
  const float* x    = (const float*)d_in[0];
  const float* Wqkv = (const float*)d_in[1];
  const float* bqkv = (const float*)d_in[2];
  const float* Wout = (const float*)d_in[3];
  const float* bout = (const float*)d_in[4];
  float* out = (float*)d_out;
  char* ws = (char*)d_ws;

  unsigned short* Acat  = (unsigned short*)(ws + 0);          // 18.9 MB (dead after gemm_qkv)
  unsigned short* BcatT = (unsigned short*)(ws + 18874368);   // 1536 rows x 2304 (7.08 MB)
  unsigned short* WvT   = (unsigned short*)(ws + 25952256);   // 1.18 MB
  float*          QKV   = (float*)(ws + 29491200);            // 37.7 MB (dead after split_qkv)
  unsigned short* Qcat  = (unsigned short*)(ws + 67239936);   // 18.9 MB
  unsigned short* Kcat  = (unsigned short*)(ws + 86114304);   // 18.9 MB
  unsigned short* VT    = (unsigned short*)(ws + 104988672);  //  6.3 MB
  unsigned short* Oemb  = (unsigned short*)(ws + 111280128);  //  6.3 MB
  unsigned short* WoutT = (unsigned short*)(ws + 117571584);  //  1.2 MB
  float*          bperm = (float*)(ws + 118751232);           //  9.2 KB
  // split-K partials alias the dead Acat/BcatT region:
  float*          Opart = (float*)(ws + 0);                   // 2 x 12.58 MB = 25.2 MB
  float*          Mlpart= (float*)(ws + 50331648);            //  0.8 MB (inside dead QKV)

  prep_fused<<<dim3(21513), 256, 0, stream>>>(x, Wqkv, Wout, bqkv,
                                              Acat, BcatT, WvT, WoutT, bperm);
  gemm_qkv<<<dim3(576), 256, 0, stream>>>(Acat, BcatT, WvT, bperm, QKV);
  split_qkv<<<dim3(9, 4096), 256, 0, stream>>>(QKV, Qcat, Kcat, VT);
  attn<<<dim3(768), 256, 0, stream>>>(Qcat, Kcat, VT, Opart, Mlpart);
  attn_combine<<<dim3(12288), 256, 0, stream>>>(Opart, Mlpart, (__bf16*)Oemb);
  gemm_bf16_128<<<dim3(6 * 32), 256, 0, stream>>>(Oemb, WoutT, bout, out, 4096, 768, 768);
}

// Round 12
// 185.603 us; speedup vs baseline: 1.4988x; 1.1577x over previous
//
#include <hip/hip_runtime.h>
#include <stdint.h>

#define LOG2E 1.44269504088896340736f

typedef __bf16 v8bf __attribute__((ext_vector_type(8)));
typedef float f32x4 __attribute__((ext_vector_type(4)));
typedef float f32x16 __attribute__((ext_vector_type(16)));
typedef unsigned int v4u __attribute__((ext_vector_type(4)));
typedef unsigned int v2u __attribute__((ext_vector_type(2)));

// ---------- helpers ----------
__device__ __forceinline__ unsigned short f2bf(float f) {
  union { float f; uint32_t u; } v; v.f = f;
  uint32_t u = v.u;
  uint32_t r = (u + 0x7FFFu + ((u >> 16) & 1u)) >> 16;   // RN-even
  return (unsigned short)r;
}
__device__ __forceinline__ float bf2f(unsigned short h) {
  union { uint32_t u; float f; } v; v.u = ((uint32_t)h) << 16;
  return v.f;
}
__device__ __forceinline__ void gll16(const void* g, void* l) {
  __builtin_amdgcn_global_load_lds(
      (const __attribute__((address_space(1))) unsigned int*)g,
      (__attribute__((address_space(3))) unsigned int*)l, 16, 0, 0);
}
__device__ __forceinline__ uint32_t pk2(float a, float b) {
  union { __bf16 h[2]; uint32_t u; } x;
  x.h[0] = (__bf16)a; x.h[1] = (__bf16)b;
  return x.u;
}

// ---------- fused prep: Acat (x -> hi|lo|hi), BcatT (qk cols, permuted), WvT, WoT ----------
__global__ void prep_fused(const float* __restrict__ x, const float* __restrict__ Wqkv,
                           const float* __restrict__ Wout,
                           unsigned short* __restrict__ Acat,
                           unsigned short* __restrict__ BcatT,
                           unsigned short* __restrict__ WvT,
                           unsigned short* __restrict__ WoT) {
  const int t = threadIdx.x, f = blockIdx.x;
  if (f < 12288) {                    // Acat
    int m = f / 3, n = (f - m * 3) * 256 + t;
    float v = x[(size_t)m * 768 + n];
    unsigned short H = f2bf(v);
    unsigned short L = f2bf(v - bf2f(H));
    size_t base = (size_t)m * 2304;
    Acat[base + n] = H;
    Acat[base + 768 + n] = L;
    Acat[base + 1536 + n] = H;
  } else if (f < 19200) {             // Wqkv columns (permuted: c'<1536 = q|k, else v)
    int g = f - 12288;
    int cp = g / 3, k = (g - cp * 3) * 256 + t;
    int n;
    if (cp < 1536) n = (cp >> 7) * 192 + (cp & 127);
    else           n = ((cp - 1536) >> 6) * 192 + 128 + ((cp - 1536) & 63);
    float v = Wqkv[(size_t)k * 2304 + n];
    unsigned short H = f2bf(v);
    if (cp < 1536) {
      unsigned short L = f2bf(v - bf2f(H));
      size_t base = (size_t)cp * 2304;
      BcatT[base + k] = H;
      BcatT[base + 768 + k] = H;
      BcatT[base + 1536 + k] = L;
    } else {
      WvT[(size_t)(cp - 1536) * 768 + k] = H;   // row = h*64+dd (global d-row)
    }
  } else {                            // Wout^T plain bf16
    int g = f - 19200;
    int n = g / 3, k = (g - n * 3) * 256 + t;
    WoT[(size_t)n * 768 + k] = f2bf(Wout[(size_t)k * 768 + n]);
  }
}

// ---------- fused QKV GEMM + split epilogues ----------
// f < 384: q|k tripled path (K=2304); epilogue splits directly into Qcat/Kcat.
// f >= 384: v path computed TRANSPOSED: VT = Wv^T x X^T (K=768); epilogue
//           writes VT[bh][dd][p] with coalesced p-runs.
__global__ __launch_bounds__(256) void gemm_qkv(
    const unsigned short* __restrict__ Acat, const unsigned short* __restrict__ BcatT,
    const unsigned short* __restrict__ WvT, const float* __restrict__ bqkv,
    unsigned short* __restrict__ Qc, unsigned short* __restrict__ Kc,
    unsigned short* __restrict__ VT) {
  __shared__ unsigned short As[128 * 32];
  __shared__ unsigned short Bs[128 * 32];
  const int t = threadIdx.x, f = blockIdx.x;
  const int w = t >> 6, l = t & 63, lr = l & 15, lg = l >> 4;
  const int wm = (w >> 1) * 64, wn = (w & 1) * 64;
  f32x4 acc[4][4] = {};

  if (f < 384) {
    // ---- tripled q|k path ----
    const int xcd = f & 7, s = f >> 3;
    const int m0 = (xcd * 4 + (s & 3)) * 128;
    const int xt = s >> 2;                       // head 0..11
    const unsigned short* Bp = BcatT + (size_t)xt * 128 * 2304;
    for (int kt = 0; kt < 72; ++kt) {
      const int k0 = kt << 5;
      const int c0 = t, c1 = t + 256;
      gll16(Acat + (size_t)(m0 + (c0 >> 2)) * 2304 + k0 + ((c0 & 3) << 3), &As[c0 * 8]);
      gll16(Acat + (size_t)(m0 + (c1 >> 2)) * 2304 + k0 + ((c1 & 3) << 3), &As[c1 * 8]);
      gll16(Bp + (size_t)(c0 >> 2) * 2304 + k0 + ((c0 & 3) << 3), &Bs[c0 * 8]);
      gll16(Bp + (size_t)(c1 >> 2) * 2304 + k0 + ((c1 & 3) << 3), &Bs[c1 * 8]);
      __syncthreads();
      v8bf a[4], b[4];
#pragma unroll
      for (int i = 0; i < 4; i++) {
        a[i] = *(const v8bf*)&As[(wm + i * 16 + lr) * 32 + lg * 8];
        b[i] = *(const v8bf*)&Bs[(wn + i * 16 + lr) * 32 + lg * 8];
      }
#pragma unroll
      for (int i = 0; i < 4; i++)
#pragma unroll
        for (int j = 0; j < 4; j++)
          acc[i][j] = __builtin_amdgcn_mfma_f32_16x16x32_bf16(a[i], b[j], acc[i][j], 0, 0, 0);
      __syncthreads();
    }
    // epilogue: split-write (wave-uniform q/k branch: wn==0 -> q, wn==64 -> k)
#pragma unroll
    for (int j = 0; j < 4; j++) {
      const int jj = j * 16 + lr;                // 0..63 within q or k
      const float bv = bqkv[xt * 192 + wn + jj];
#pragma unroll
      for (int i = 0; i < 4; i++) {
#pragma unroll
        for (int r = 0; r < 4; r++) {
          const int m = m0 + wm + i * 16 + lg * 4 + r;
          const int b = m >> 11, p = m & 2047;
          size_t base = ((size_t)(b * 12 + xt) * 2048 + p) * 192;
          float val = acc[i][j][r] + bv;
          if (wn == 0) {                         // q: fold 8*log2e, split hi/lo/hi
            val *= (8.0f * LOG2E);
            unsigned short H = f2bf(val);
            unsigned short L = f2bf(val - bf2f(H));
            Qc[base + jj] = H; Qc[base + 64 + jj] = L; Qc[base + 128 + jj] = H;
          } else {                               // k: split hi/hi/lo
            unsigned short H = f2bf(val);
            unsigned short L = f2bf(val - bf2f(H));
            Kc[base + jj] = H; Kc[base + 64 + jj] = H; Kc[base + 128 + jj] = L;
          }
        }
      }
    }
  } else {
    // ---- v path, transposed: C'[d][m] = WvT x Acat-hi^T ----
    const int g = f - 384;
    const int xcd = g & 7, s = g >> 3;           // s 0..23
    const int m0v = (xcd * 4 + (s & 3)) * 128;   // m-tile 0..31
    const int d0 = (s >> 2) * 128;               // d-tile 0..5
    for (int kt = 0; kt < 24; ++kt) {
      const int k0 = kt << 5;
      const int c0 = t, c1 = t + 256;
      gll16(WvT + (size_t)(d0 + (c0 >> 2)) * 768 + k0 + ((c0 & 3) << 3), &As[c0 * 8]);
      gll16(WvT + (size_t)(d0 + (c1 >> 2)) * 768 + k0 + ((c1 & 3) << 3), &As[c1 * 8]);
      gll16(Acat + (size_t)(m0v + (c0 >> 2)) * 2304 + k0 + ((c0 & 3) << 3), &Bs[c0 * 8]);
      gll16(Acat + (size_t)(m0v + (c1 >> 2)) * 2304 + k0 + ((c1 & 3) << 3), &Bs[c1 * 8]);
      __syncthreads();
      v8bf a[4], b[4];
#pragma unroll
      for (int i = 0; i < 4; i++) {
        a[i] = *(const v8bf*)&As[(wm + i * 16 + lr) * 32 + lg * 8];
        b[i] = *(const v8bf*)&Bs[(wn + i * 16 + lr) * 32 + lg * 8];
      }
#pragma unroll
      for (int i = 0; i < 4; i++)
#pragma unroll
        for (int j = 0; j < 4; j++)
          acc[i][j] = __builtin_amdgcn_mfma_f32_16x16x32_bf16(a[i], b[j], acc[i][j], 0, 0, 0);
      __syncthreads();
    }
    // epilogue: rows = d (h*64+dd), cols = m -> VT[bh][dd][p], p coalesced
#pragma unroll
    for (int i = 0; i < 4; i++) {
#pragma unroll
      for (int r = 0; r < 4; r++) {
        const int drow = d0 + wm + i * 16 + lg * 4 + r;
        const int h = drow >> 6, dd = drow & 63;
        const float bv = bqkv[h * 192 + 128 + dd];
#pragma unroll
        for (int j = 0; j < 4; j++) {
          const int m = m0v + wn + j * 16 + lr;
          const int b = m >> 11, p = m & 2047;
          VT[((size_t)(b * 12 + h) * 64 + dd) * 2048 + p] = f2bf(acc[i][j][r] + bv);
        }
      }
    }
  }
}

// ---------- out-proj GEMM: 64x128 tiles, 384 blocks ----------
// Staging: As = 64 rows x 4 chunks = 256 chunks (1/thread);
//          Bs = 128 rows x 4 chunks = 512 chunks (2/thread).  [R11 bug fixed]
__global__ __launch_bounds__(256) void gemm_out(
    const unsigned short* __restrict__ A, const unsigned short* __restrict__ B,
    const float* __restrict__ bias, float* __restrict__ C) {
  __shared__ unsigned short As[64 * 32];
  __shared__ unsigned short Bs[128 * 32];
  const int t = threadIdx.x, f = blockIdx.x;
  const int xcd = f & 7, s = f >> 3;             // s 0..47
  const int m0 = (xcd * 8 + (s & 7)) * 64;       // 64 m-tiles
  const int n0 = (s >> 3) * 128;                 // 6 n-tiles
  const int w = t >> 6, l = t & 63, lr = l & 15, lg = l >> 4;
  const int wm = (w >> 1) * 32, wn = (w & 1) * 64;
  f32x4 acc[2][4] = {};
  for (int kt = 0; kt < 24; ++kt) {
    const int k0 = kt << 5;
    gll16(A + (size_t)(m0 + (t >> 2)) * 768 + k0 + ((t & 3) << 3), &As[t * 8]);
    gll16(B + (size_t)(n0 + (t >> 2)) * 768 + k0 + ((t & 3) << 3), &Bs[t * 8]);
    gll16(B + (size_t)(n0 + 64 + (t >> 2)) * 768 + k0 + ((t & 3) << 3), &Bs[(t + 256) * 8]);
    __syncthreads();
    v8bf a[2], b[4];
#pragma unroll
    for (int i = 0; i < 2; i++)
      a[i] = *(const v8bf*)&As[(wm + i * 16 + lr) * 32 + lg * 8];
#pragma unroll
    for (int j = 0; j < 4; j++)
      b[j] = *(const v8bf*)&Bs[(wn + j * 16 + lr) * 32 + lg * 8];
#pragma unroll
    for (int i = 0; i < 2; i++)
#pragma unroll
      for (int j = 0; j < 4; j++)
        acc[i][j] = __builtin_amdgcn_mfma_f32_16x16x32_bf16(a[i], b[j], acc[i][j], 0, 0, 0);
    __syncthreads();
  }
#pragma unroll
  for (int i = 0; i < 2; i++) {
#pragma unroll
    for (int j = 0; j < 4; j++) {
      const int col = n0 + wn + j * 16 + lr;
      const float bv = bias[col];
#pragma unroll
      for (int r = 0; r < 4; r++) {
        const int row = m0 + wm + i * 16 + lg * 4 + r;
        C[(size_t)row * 768 + col] = acc[i][j][r] + bv;
      }
    }
  }
}

// ---------- flash attention: KVBLK=32, log2-domain softmax, 3 blocks/CU ----------
__global__ __launch_bounds__(256, 3) void attn(
    const unsigned short* __restrict__ Qc, const unsigned short* __restrict__ Kc,
    const unsigned short* __restrict__ VT,
    float* __restrict__ Op, float* __restrict__ Ml) {
  __shared__ __align__(16) unsigned short Ks[2][32 * 192];
  __shared__ __align__(16) unsigned short Vs[2][64 * 32];
  __shared__ float Al[4][32];
  const int t = threadIdx.x, w = t >> 6, l = t & 63;
  const int lq = l & 31, hi = l >> 5;
  const int f = blockIdx.x;
  const int xcd = f & 7, slot = f >> 3;
  const int p = xcd + 8 * (slot >> 4);      // 0..47: (bh,split) pair
  const int bh = p >> 1, zsplit = p & 1;
  const int q0 = (slot & 15) * 128;
  const int qw0 = q0 + w * 32;
  const int NKT = 32;
  const int ktBase = zsplit * 32;
  const unsigned short* Qb = Qc + (size_t)bh * 2048 * 192;
  const unsigned short* Kb = Kc + (size_t)bh * 2048 * 192;
  const unsigned short* Vb = VT + (size_t)bh * 64 * 2048;

  int kwofs[3];
#pragma unroll
  for (int i = 0; i < 3; i++) {
    int c = t + i * 256;
    int row = c / 24, cc = c - row * 24;
    kwofs[i] = (row * 192 + cc * 8) ^ ((row & 7) << 3);
  }
  const int vd = t >> 2, vpart = t & 3;
  const int vwofs = (vd * 32 + vpart * 8) ^ ((vd & 3) << 3);

  const char* gK = (const char*)Kb + (size_t)ktBase * 12288 + (size_t)t * 16;
  const char* gV = (const char*)Vb + (size_t)vd * 4096 + (size_t)vpart * 16
                   + (size_t)ktBase * 64;

  v4u kreg[3], vreg;
#pragma unroll
  for (int i = 0; i < 3; i++) kreg[i] = *(const v4u*)(gK + i * 4096);
  vreg = *(const v4u*)gV;
#pragma unroll
  for (int i = 0; i < 3; i++) *(v4u*)&Ks[0][kwofs[i]] = kreg[i];
  *(v4u*)&Vs[0][vwofs] = vreg;
  gK += 12288; gV += 64;
#pragma unroll
  for (int i = 0; i < 3; i++) kreg[i] = *(const v4u*)(gK + i * 4096);
  vreg = *(const v4u*)gV;

  v8bf qf[12];
#pragma unroll
  for (int ks = 0; ks < 12; ++ks)
    qf[ks] = *(const v8bf*)(Qb + (size_t)(qw0 + lq) * 192 + ks * 16 + hi * 8);

  f32x16 o0 = {}, o1 = {};
  float mrun = -1e30f, lsum = 0.f;
  const int sxk = (lq & 7) << 3;
  const int sxv = (lq & 3) << 3;
  __syncthreads();

  for (int kt = 0; kt < NKT; ++kt) {
    const unsigned short* ksb = &Ks[kt & 1][0];
    const unsigned short* vsb = &Vs[kt & 1][0];
    unsigned short* ksw = &Ks[(kt & 1) ^ 1][0];
    unsigned short* vsw = &Vs[(kt & 1) ^ 1][0];

    // S^T(log2) = K Q^T
    f32x16 s = {};
    __builtin_amdgcn_s_setprio(1);
#pragma unroll
    for (int ks = 0; ks < 12; ++ks) {
      v8bf ka = *(const v8bf*)&ksb[(lq * 192 + ks * 16 + hi * 8) ^ sxk];
      s = __builtin_amdgcn_mfma_f32_32x32x16_bf16(ka, qf[ks], s, 0, 0, 0);
    }
    __builtin_amdgcn_s_setprio(0);

    if (kt < NKT - 1) {
#pragma unroll
      for (int i = 0; i < 3; i++) *(v4u*)&ksw[kwofs[i]] = kreg[i];
      *(v4u*)&vsw[vwofs] = vreg;
    }
    if (kt < NKT - 2) {
      gK += 12288; gV += 64;
#pragma unroll
      for (int i = 0; i < 3; i++) kreg[i] = *(const v4u*)(gK + i * 4096);
      vreg = *(const v4u*)gV;
    }

    // lane-local max (tree) + one half-swap
    float tm[8];
#pragma unroll
    for (int i = 0; i < 8; i++) tm[i] = fmaxf(s[i], s[i + 8]);
#pragma unroll
    for (int i = 0; i < 4; i++) tm[i] = fmaxf(tm[i], tm[i + 4]);
    float pmax = fmaxf(fmaxf(tm[0], tm[1]), fmaxf(tm[2], tm[3]));
    {
      v2u r = __builtin_amdgcn_permlane32_swap(__float_as_uint(pmax),
                                               __float_as_uint(pmax), false, false);
      pmax = fmaxf(__uint_as_float(r.x), __uint_as_float(r.y));
    }

    // T13 defer-max, THR=32 (log2 units)
    if (__any(pmax > mrun + 32.f)) {
      float mnew = fmaxf(mrun, pmax);
      float a = __builtin_exp2f(mrun - mnew);
      mrun = mnew;
      lsum *= a;
      if (!hi) Al[w][lq] = a;
#pragma unroll
      for (int r = 0; r < 16; r++) {
        float ar = Al[w][(r & 3) + 8 * (r >> 2) + 4 * hi];
        o0[r] *= ar; o1[r] *= ar;
      }
    }

    // P = exp2(S - m) in-place, tree sum, pack PV A-frags
#pragma unroll
    for (int i = 0; i < 16; i++) s[i] = __builtin_exp2f(s[i] - mrun);
    {
      float a0 = (s[0] + s[8]) + (s[1] + s[9]);
      float a1 = (s[2] + s[10]) + (s[3] + s[11]);
      float a2 = (s[4] + s[12]) + (s[5] + s[13]);
      float a3 = (s[6] + s[14]) + (s[7] + s[15]);
      float ps = (a0 + a1) + (a2 + a3);
      v2u r = __builtin_amdgcn_permlane32_swap(__float_as_uint(ps),
                                               __float_as_uint(ps), false, false);
      lsum += __uint_as_float(r.x) + __uint_as_float(r.y);
    }
    uint32_t paw[2][4];
    {
      v2u r0 = __builtin_amdgcn_permlane32_swap(pk2(s[0], s[1]), pk2(s[4], s[5]), false, false);
      v2u r1 = __builtin_amdgcn_permlane32_swap(pk2(s[2], s[3]), pk2(s[6], s[7]), false, false);
      paw[0][0] = r0.x; paw[0][2] = r0.y; paw[0][1] = r1.x; paw[0][3] = r1.y;
      v2u r2 = __builtin_amdgcn_permlane32_swap(pk2(s[8], s[9]), pk2(s[12], s[13]), false, false);
      v2u r3 = __builtin_amdgcn_permlane32_swap(pk2(s[10], s[11]), pk2(s[14], s[15]), false, false);
      paw[1][0] = r2.x; paw[1][2] = r2.y; paw[1][1] = r3.x; paw[1][3] = r3.y;
    }

    // O += P V
    __builtin_amdgcn_s_setprio(1);
#pragma unroll
    for (int ks = 0; ks < 2; ++ks) {
      union { uint32_t u[4]; v8bf v; } pa;
      pa.u[0] = paw[ks][0]; pa.u[1] = paw[ks][1];
      pa.u[2] = paw[ks][2]; pa.u[3] = paw[ks][3];
      v8bf v0 = *(const v8bf*)&vsb[(lq * 32 + ks * 16 + hi * 8) ^ sxv];
      v8bf v1 = *(const v8bf*)&vsb[((lq + 32) * 32 + ks * 16 + hi * 8) ^ sxv];
      o0 = __builtin_amdgcn_mfma_f32_32x32x16_bf16(pa.v, v0, o0, 0, 0, 0);
      o1 = __builtin_amdgcn_mfma_f32_32x32x16_bf16(pa.v, v1, o1, 0, 0, 0);
    }
    __builtin_amdgcn_s_setprio(0);
    if (kt < NKT - 1) __syncthreads();
  }

  // epilogue: partial O + (m in log2 units, l)
  const size_t S = (size_t)24 * 2048;
  const size_t srow = (size_t)zsplit * S + (size_t)bh * 2048;
  if (!hi) {
    Ml[(srow + qw0 + lq) * 2]     = mrun;
    Ml[(srow + qw0 + lq) * 2 + 1] = lsum;
  }
#pragma unroll
  for (int r = 0; r < 16; r++) {
    const int q = qw0 + (r & 3) + 8 * (r >> 2) + 4 * hi;
    Op[(srow + q) * 64 + lq]      = o0[r];
    Op[(srow + q) * 64 + 32 + lq] = o1[r];
  }
}

// ---------- combine the two split-K partials (m in log2 units) ----------
__global__ __launch_bounds__(256) void attn_combine(
    const float* __restrict__ Op, const float* __restrict__ Ml,
    __bf16* __restrict__ Oe) {
  const size_t S = (size_t)24 * 2048;
  int row = blockIdx.x * 4 + (threadIdx.x >> 6);
  int lane = threadIdx.x & 63;
  int bh = row >> 11, q = row & 2047;
  int b = bh / 12, h = bh - b * 12;
  float m1 = Ml[(size_t)row * 2], l1 = Ml[(size_t)row * 2 + 1];
  float m2 = Ml[(S + row) * 2],   l2 = Ml[(S + row) * 2 + 1];
  float M = fmaxf(m1, m2);
  float a1 = __builtin_exp2f(m1 - M);
  float a2 = __builtin_exp2f(m2 - M);
  float rinv = 1.0f / (l1 * a1 + l2 * a2);
  float o1 = Op[(size_t)row * 64 + lane];
  float o2 = Op[S * 64 + (size_t)row * 64 + lane];
  Oe[((size_t)(b * 2048 + q)) * 768 + h * 64 + lane] = (__bf16)((o1 * a1 + o2 * a2) * rinv);
}

// ---------- launcher ----------
extern "C" void kernel_launch(void* const* d_in, const int* in_sizes, int n_in,
                              void* d_out, int out_size, void* d_ws, size_t ws_size,
                              hipStream_t stream) {
  const float* x    = (const float*)d_in[0];
  const float* Wqkv = (const float*)d_in[1];
  const float* bqkv = (const float*)d_in[2];
  const float* Wout = (const float*)d_in[3];
  const float* bout = (const float*)d_in[4];
  float* out = (float*)d_out;
  char* ws = (char*)d_ws;

  unsigned short* Acat  = (unsigned short*)(ws + 0);          // 18.9 MB (dead after gemm_qkv)
  unsigned short* BcatT = (unsigned short*)(ws + 18874368);   // 1536 x 2304 (7.08 MB)
  unsigned short* WvT   = (unsigned short*)(ws + 25952256);   // 1.18 MB
  unsigned short* Qcat  = (unsigned short*)(ws + 67239936);   // 18.9 MB
  unsigned short* Kcat  = (unsigned short*)(ws + 86114304);   // 18.9 MB
  unsigned short* VT    = (unsigned short*)(ws + 104988672);  //  6.3 MB
  unsigned short* Oemb  = (unsigned short*)(ws + 111280128);  //  6.3 MB
  unsigned short* WoutT = (unsigned short*)(ws + 117571584);  //  1.2 MB
  // split-K partials alias the dead Acat/BcatT region (attn runs after gemm_qkv):
  float*          Opart = (float*)(ws + 0);                   // 2 x 12.58 MB = 25.2 MB
  float*          Mlpart= (float*)(ws + 50331648);            //  0.8 MB (dead region)

  prep_fused<<<dim3(21504), 256, 0, stream>>>(x, Wqkv, Wout, Acat, BcatT, WvT, WoutT);
  gemm_qkv<<<dim3(576), 256, 0, stream>>>(Acat, BcatT, WvT, bqkv, Qcat, Kcat, VT);
  attn<<<dim3(768), 256, 0, stream>>>(Qcat, Kcat, VT, Opart, Mlpart);
  attn_combine<<<dim3(12288), 256, 0, stream>>>(Opart, Mlpart, (__bf16*)Oemb);
  gemm_out<<<dim3(384), 256, 0, stream>>>(Oemb, WoutT, bout, out);
}

// Round 13
// 156.494 us; speedup vs baseline: 1.7776x; 1.1860x over previous
//
#include <hip/hip_runtime.h>
#include <stdint.h>

#define LOG2E 1.44269504088896340736f

typedef __bf16 v8bf __attribute__((ext_vector_type(8)));
typedef _Float16 v8h __attribute__((ext_vector_type(8)));
typedef float f32x4 __attribute__((ext_vector_type(4)));
typedef float f32x16 __attribute__((ext_vector_type(16)));
typedef unsigned int v4u __attribute__((ext_vector_type(4)));
typedef unsigned int v2u __attribute__((ext_vector_type(2)));

// ---------- helpers ----------
__device__ __forceinline__ unsigned short f2bf(float f) {
  union { float f; uint32_t u; } v; v.f = f;
  uint32_t u = v.u;
  uint32_t r = (u + 0x7FFFu + ((u >> 16) & 1u)) >> 16;   // RN-even
  return (unsigned short)r;
}
__device__ __forceinline__ float bf2f(unsigned short h) {
  union { uint32_t u; float f; } v; v.u = ((uint32_t)h) << 16;
  return v.f;
}
__device__ __forceinline__ void gll16(const void* g, void* l) {
  __builtin_amdgcn_global_load_lds(
      (const __attribute__((address_space(1))) unsigned int*)g,
      (__attribute__((address_space(3))) unsigned int*)l, 16, 0, 0);
}
__device__ __forceinline__ uint32_t pk2(float a, float b) {
  union { __bf16 h[2]; uint32_t u; } x;
  x.h[0] = (__bf16)a; x.h[1] = (__bf16)b;
  return x.u;
}

// ---------- fused prep: Acat (x -> hi|lo|hi), BcatT (qk cols, permuted), WvT, WoT ----------
__global__ void prep_fused(const float* __restrict__ x, const float* __restrict__ Wqkv,
                           const float* __restrict__ Wout,
                           unsigned short* __restrict__ Acat,
                           unsigned short* __restrict__ BcatT,
                           unsigned short* __restrict__ WvT,
                           unsigned short* __restrict__ WoT) {
  const int t = threadIdx.x, f = blockIdx.x;
  if (f < 12288) {                    // Acat
    int m = f / 3, n = (f - m * 3) * 256 + t;
    float v = x[(size_t)m * 768 + n];
    unsigned short H = f2bf(v);
    unsigned short L = f2bf(v - bf2f(H));
    size_t base = (size_t)m * 2304;
    Acat[base + n] = H;
    Acat[base + 768 + n] = L;
    Acat[base + 1536 + n] = H;
  } else if (f < 19200) {             // Wqkv columns (permuted: c'<1536 = q|k, else v)
    int g = f - 12288;
    int cp = g / 3, k = (g - cp * 3) * 256 + t;
    int n;
    if (cp < 1536) n = (cp >> 7) * 192 + (cp & 127);
    else           n = ((cp - 1536) >> 6) * 192 + 128 + ((cp - 1536) & 63);
    float v = Wqkv[(size_t)k * 2304 + n];
    unsigned short H = f2bf(v);
    if (cp < 1536) {
      unsigned short L = f2bf(v - bf2f(H));
      size_t base = (size_t)cp * 2304;
      BcatT[base + k] = H;
      BcatT[base + 768 + k] = H;
      BcatT[base + 1536 + k] = L;
    } else {
      WvT[(size_t)(cp - 1536) * 768 + k] = H;   // row = h*64+dd (global d-row)
    }
  } else {                            // Wout^T plain bf16
    int g = f - 19200;
    int n = g / 3, k = (g - n * 3) * 256 + t;
    WoT[(size_t)n * 768 + k] = f2bf(Wout[(size_t)k * 768 + n]);
  }
}

// ---------- fused QKV GEMM + split epilogues ----------
// f < 384: q|k tripled path (K=2304); epilogue writes SINGLE fp16 Qh/Kh
//          (q folded by 8*log2e). fp16's 11-bit mantissa gives logit noise
//          sigma ~0.02 log2-units — well within the 0.106 threshold budget.
// f >= 384: v path computed TRANSPOSED: VT = Wv^T x X^T (K=768, bf16 out).
__global__ __launch_bounds__(256) void gemm_qkv(
    const unsigned short* __restrict__ Acat, const unsigned short* __restrict__ BcatT,
    const unsigned short* __restrict__ WvT, const float* __restrict__ bqkv,
    _Float16* __restrict__ Qh, _Float16* __restrict__ Kh,
    unsigned short* __restrict__ VT) {
  __shared__ unsigned short As[128 * 32];
  __shared__ unsigned short Bs[128 * 32];
  const int t = threadIdx.x, f = blockIdx.x;
  const int w = t >> 6, l = t & 63, lr = l & 15, lg = l >> 4;
  const int wm = (w >> 1) * 64, wn = (w & 1) * 64;
  f32x4 acc[4][4] = {};

  if (f < 384) {
    // ---- tripled q|k path ----
    const int xcd = f & 7, s = f >> 3;
    const int m0 = (xcd * 4 + (s & 3)) * 128;
    const int xt = s >> 2;                       // head 0..11
    const unsigned short* Bp = BcatT + (size_t)xt * 128 * 2304;
    for (int kt = 0; kt < 72; ++kt) {
      const int k0 = kt << 5;
      const int c0 = t, c1 = t + 256;
      gll16(Acat + (size_t)(m0 + (c0 >> 2)) * 2304 + k0 + ((c0 & 3) << 3), &As[c0 * 8]);
      gll16(Acat + (size_t)(m0 + (c1 >> 2)) * 2304 + k0 + ((c1 & 3) << 3), &As[c1 * 8]);
      gll16(Bp + (size_t)(c0 >> 2) * 2304 + k0 + ((c0 & 3) << 3), &Bs[c0 * 8]);
      gll16(Bp + (size_t)(c1 >> 2) * 2304 + k0 + ((c1 & 3) << 3), &Bs[c1 * 8]);
      __syncthreads();
      v8bf a[4], b[4];
#pragma unroll
      for (int i = 0; i < 4; i++) {
        a[i] = *(const v8bf*)&As[(wm + i * 16 + lr) * 32 + lg * 8];
        b[i] = *(const v8bf*)&Bs[(wn + i * 16 + lr) * 32 + lg * 8];
      }
#pragma unroll
      for (int i = 0; i < 4; i++)
#pragma unroll
        for (int j = 0; j < 4; j++)
          acc[i][j] = __builtin_amdgcn_mfma_f32_16x16x32_bf16(a[i], b[j], acc[i][j], 0, 0, 0);
      __syncthreads();
    }
    // epilogue: single fp16 write (wave-uniform q/k branch)
#pragma unroll
    for (int j = 0; j < 4; j++) {
      const int jj = j * 16 + lr;                // 0..63 within q or k
      const float bv = bqkv[xt * 192 + wn + jj];
#pragma unroll
      for (int i = 0; i < 4; i++) {
#pragma unroll
        for (int r = 0; r < 4; r++) {
          const int m = m0 + wm + i * 16 + lg * 4 + r;
          const int b = m >> 11, p = m & 2047;
          size_t base = ((size_t)(b * 12 + xt) * 2048 + p) * 64;
          float val = acc[i][j][r] + bv;
          if (wn == 0) {
            Qh[base + jj] = (_Float16)(val * (8.0f * LOG2E));
          } else {
            Kh[base + jj] = (_Float16)val;
          }
        }
      }
    }
  } else {
    // ---- v path, transposed: C'[d][m] = WvT x Acat-hi^T ----
    const int g = f - 384;
    const int xcd = g & 7, s = g >> 3;           // s 0..23
    const int m0v = (xcd * 4 + (s & 3)) * 128;   // m-tile 0..31
    const int d0 = (s >> 2) * 128;               // d-tile 0..5
    for (int kt = 0; kt < 24; ++kt) {
      const int k0 = kt << 5;
      const int c0 = t, c1 = t + 256;
      gll16(WvT + (size_t)(d0 + (c0 >> 2)) * 768 + k0 + ((c0 & 3) << 3), &As[c0 * 8]);
      gll16(WvT + (size_t)(d0 + (c1 >> 2)) * 768 + k0 + ((c1 & 3) << 3), &As[c1 * 8]);
      gll16(Acat + (size_t)(m0v + (c0 >> 2)) * 2304 + k0 + ((c0 & 3) << 3), &Bs[c0 * 8]);
      gll16(Acat + (size_t)(m0v + (c1 >> 2)) * 2304 + k0 + ((c1 & 3) << 3), &Bs[c1 * 8]);
      __syncthreads();
      v8bf a[4], b[4];
#pragma unroll
      for (int i = 0; i < 4; i++) {
        a[i] = *(const v8bf*)&As[(wm + i * 16 + lr) * 32 + lg * 8];
        b[i] = *(const v8bf*)&Bs[(wn + i * 16 + lr) * 32 + lg * 8];
      }
#pragma unroll
      for (int i = 0; i < 4; i++)
#pragma unroll
        for (int j = 0; j < 4; j++)
          acc[i][j] = __builtin_amdgcn_mfma_f32_16x16x32_bf16(a[i], b[j], acc[i][j], 0, 0, 0);
      __syncthreads();
    }
    // epilogue: rows = d (h*64+dd), cols = m -> VT[bh][dd][p], p coalesced
#pragma unroll
    for (int i = 0; i < 4; i++) {
#pragma unroll
      for (int r = 0; r < 4; r++) {
        const int drow = d0 + wm + i * 16 + lg * 4 + r;
        const int h = drow >> 6, dd = drow & 63;
        const float bv = bqkv[h * 192 + 128 + dd];
#pragma unroll
        for (int j = 0; j < 4; j++) {
          const int m = m0v + wn + j * 16 + lr;
          const int b = m >> 11, p = m & 2047;
          VT[((size_t)(b * 12 + h) * 64 + dd) * 2048 + p] = f2bf(acc[i][j][r] + bv);
        }
      }
    }
  }
}

// ---------- out-proj GEMM: 64x128 tiles, 384 blocks ----------
__global__ __launch_bounds__(256) void gemm_out(
    const unsigned short* __restrict__ A, const unsigned short* __restrict__ B,
    const float* __restrict__ bias, float* __restrict__ C) {
  __shared__ unsigned short As[64 * 32];
  __shared__ unsigned short Bs[128 * 32];
  const int t = threadIdx.x, f = blockIdx.x;
  const int xcd = f & 7, s = f >> 3;             // s 0..47
  const int m0 = (xcd * 8 + (s & 7)) * 64;       // 64 m-tiles
  const int n0 = (s >> 3) * 128;                 // 6 n-tiles
  const int w = t >> 6, l = t & 63, lr = l & 15, lg = l >> 4;
  const int wm = (w >> 1) * 32, wn = (w & 1) * 64;
  f32x4 acc[2][4] = {};
  for (int kt = 0; kt < 24; ++kt) {
    const int k0 = kt << 5;
    gll16(A + (size_t)(m0 + (t >> 2)) * 768 + k0 + ((t & 3) << 3), &As[t * 8]);
    gll16(B + (size_t)(n0 + (t >> 2)) * 768 + k0 + ((t & 3) << 3), &Bs[t * 8]);
    gll16(B + (size_t)(n0 + 64 + (t >> 2)) * 768 + k0 + ((t & 3) << 3), &Bs[(t + 256) * 8]);
    __syncthreads();
    v8bf a[2], b[4];
#pragma unroll
    for (int i = 0; i < 2; i++)
      a[i] = *(const v8bf*)&As[(wm + i * 16 + lr) * 32 + lg * 8];
#pragma unroll
    for (int j = 0; j < 4; j++)
      b[j] = *(const v8bf*)&Bs[(wn + j * 16 + lr) * 32 + lg * 8];
#pragma unroll
    for (int i = 0; i < 2; i++)
#pragma unroll
      for (int j = 0; j < 4; j++)
        acc[i][j] = __builtin_amdgcn_mfma_f32_16x16x32_bf16(a[i], b[j], acc[i][j], 0, 0, 0);
    __syncthreads();
  }
#pragma unroll
  for (int i = 0; i < 2; i++) {
#pragma unroll
    for (int j = 0; j < 4; j++) {
      const int col = n0 + wn + j * 16 + lr;
      const float bv = bias[col];
#pragma unroll
      for (int r = 0; r < 4; r++) {
        const int row = m0 + wm + i * 16 + lg * 4 + r;
        C[(size_t)row * 768 + col] = acc[i][j][r] + bv;
      }
    }
  }
}

// ---------- flash attention: fp16 QK^T (K=64), KVBLK=32, split-K x4 ----------
// Flat grid 1536 = 8 xcd x 24 pairGroups x 16 q-tiles (pair p = bh*4 + zsplit;
// 16 sharers of one pair on one XCD). NKT=16 tiles of 32 keys per split.
// QK^T: 4x mfma_f32_32x32x16_f16; softmax in log2 domain; PV stays bf16.
__global__ __launch_bounds__(256, 4) void attn(
    const _Float16* __restrict__ Qh, const _Float16* __restrict__ Kh,
    const unsigned short* __restrict__ VT,
    float* __restrict__ Op, float* __restrict__ Ml) {
  __shared__ __align__(16) _Float16 Ks[2][32 * 64];
  __shared__ __align__(16) unsigned short Vs[2][64 * 32];
  __shared__ float Al[4][32];
  const int t = threadIdx.x, w = t >> 6, l = t & 63;
  const int lq = l & 31, hi = l >> 5;
  const int f = blockIdx.x;
  const int xcd = f & 7, slot = f >> 3;
  const int p = xcd + 8 * (slot >> 4);      // 0..95: (bh,split) pair
  const int bh = p >> 2, zsplit = p & 3;
  const int q0 = (slot & 15) * 128;
  const int qw0 = q0 + w * 32;
  const int NKT = 16;
  const int ktBase = zsplit * 16;           // 16 key-tiles of 32 keys per split
  const _Float16* Qb = Qh + (size_t)bh * 2048 * 64;
  const _Float16* Kb = Kh + (size_t)bh * 2048 * 64;
  const unsigned short* Vb = VT + (size_t)bh * 64 * 2048;

  // swizzled LDS write offsets (element units)
  const int krow = t >> 3, kpart = t & 7;   // 8 chunks per 64-elem fp16 K row
  const int kwofs = (krow * 64 + kpart * 8) ^ ((krow & 7) << 3);
  const int vd = t >> 2, vpart = t & 3;     // 4 chunks per 32-elem V row
  const int vwofs = (vd * 32 + vpart * 8) ^ ((vd & 3) << 3);

  // linear global source pointers (coalesced), bumped per kt
  const char* gK = (const char*)Kb + (size_t)ktBase * 4096 + (size_t)t * 16;
  const char* gV = (const char*)Vb + (size_t)vd * 4096 + (size_t)vpart * 16
                   + (size_t)ktBase * 64;

  v4u kreg, vreg;
  kreg = *(const v4u*)gK;
  vreg = *(const v4u*)gV;
  *(v4u*)&Ks[0][kwofs] = kreg;
  *(v4u*)&Vs[0][vwofs] = vreg;
  gK += 4096; gV += 64;
  kreg = *(const v4u*)gK;
  vreg = *(const v4u*)gV;

  // Q B-frags (fp16): lane holds Q[qw0+lq][ks*16 + hi*8 .. +7]
  v8h qf[4];
#pragma unroll
  for (int ks = 0; ks < 4; ++ks)
    qf[ks] = *(const v8h*)(Qb + (size_t)(qw0 + lq) * 64 + ks * 16 + hi * 8);

  f32x16 o0 = {}, o1 = {};
  float mrun = -1e30f, lsum = 0.f;
  const int sxk = (lq & 7) << 3;            // K read swizzle (rows = lq)
  const int sxv = (lq & 3) << 3;            // V read swizzle (rows = lq, lq+32)
  __syncthreads();

  for (int kt = 0; kt < NKT; ++kt) {
    const _Float16* ksb = &Ks[kt & 1][0];
    const unsigned short* vsb = &Vs[kt & 1][0];
    _Float16* ksw = &Ks[(kt & 1) ^ 1][0];
    unsigned short* vsw = &Vs[(kt & 1) ^ 1][0];

    // S^T(log2) = K Q^T  (fp16, K=64 -> 4 MFMA)
    f32x16 s = {};
    __builtin_amdgcn_s_setprio(1);
#pragma unroll
    for (int ks = 0; ks < 4; ++ks) {
      v8h ka = *(const v8h*)&ksb[(lq * 64 + ks * 16 + hi * 8) ^ sxk];
      s = __builtin_amdgcn_mfma_f32_32x32x16_f16(ka, qf[ks], s, 0, 0, 0);
    }
    __builtin_amdgcn_s_setprio(0);

    // stage tile kt+1 into the other buffer (overlaps compute)
    if (kt < NKT - 1) {
      *(v4u*)&ksw[kwofs] = kreg;
      *(v4u*)&vsw[vwofs] = vreg;
    }
    if (kt < NKT - 2) {
      gK += 4096; gV += 64;
      kreg = *(const v4u*)gK;
      vreg = *(const v4u*)gV;
    }

    // lane-local max (tree) + one half-swap
    float tm[8];
#pragma unroll
    for (int i = 0; i < 8; i++) tm[i] = fmaxf(s[i], s[i + 8]);
#pragma unroll
    for (int i = 0; i < 4; i++) tm[i] = fmaxf(tm[i], tm[i + 4]);
    float pmax = fmaxf(fmaxf(tm[0], tm[1]), fmaxf(tm[2], tm[3]));
    {
      v2u r = __builtin_amdgcn_permlane32_swap(__float_as_uint(pmax),
                                               __float_as_uint(pmax), false, false);
      pmax = fmaxf(__uint_as_float(r.x), __uint_as_float(r.y));
    }

    // T13 defer-max, THR=32 (log2 units)
    if (__any(pmax > mrun + 32.f)) {
      float mnew = fmaxf(mrun, pmax);
      float a = __builtin_exp2f(mrun - mnew);
      mrun = mnew;
      lsum *= a;
      if (!hi) Al[w][lq] = a;
#pragma unroll
      for (int r = 0; r < 16; r++) {
        float ar = Al[w][(r & 3) + 8 * (r >> 2) + 4 * hi];
        o0[r] *= ar; o1[r] *= ar;
      }
    }

    // P = exp2(S - m) in-place, tree sum, pack PV A-frags
#pragma unroll
    for (int i = 0; i < 16; i++) s[i] = __builtin_exp2f(s[i] - mrun);
    {
      float a0 = (s[0] + s[8]) + (s[1] + s[9]);
      float a1 = (s[2] + s[10]) + (s[3] + s[11]);
      float a2 = (s[4] + s[12]) + (s[5] + s[13]);
      float a3 = (s[6] + s[14]) + (s[7] + s[15]);
      float ps = (a0 + a1) + (a2 + a3);
      v2u r = __builtin_amdgcn_permlane32_swap(__float_as_uint(ps),
                                               __float_as_uint(ps), false, false);
      lsum += __uint_as_float(r.x) + __uint_as_float(r.y);
    }
    uint32_t paw[2][4];
    {
      v2u r0 = __builtin_amdgcn_permlane32_swap(pk2(s[0], s[1]), pk2(s[4], s[5]), false, false);
      v2u r1 = __builtin_amdgcn_permlane32_swap(pk2(s[2], s[3]), pk2(s[6], s[7]), false, false);
      paw[0][0] = r0.x; paw[0][2] = r0.y; paw[0][1] = r1.x; paw[0][3] = r1.y;
      v2u r2 = __builtin_amdgcn_permlane32_swap(pk2(s[8], s[9]), pk2(s[12], s[13]), false, false);
      v2u r3 = __builtin_amdgcn_permlane32_swap(pk2(s[10], s[11]), pk2(s[14], s[15]), false, false);
      paw[1][0] = r2.x; paw[1][2] = r2.y; paw[1][1] = r3.x; paw[1][3] = r3.y;
    }

    // O += P V  (bf16)
    __builtin_amdgcn_s_setprio(1);
#pragma unroll
    for (int ks = 0; ks < 2; ++ks) {
      union { uint32_t u[4]; v8bf v; } pa;
      pa.u[0] = paw[ks][0]; pa.u[1] = paw[ks][1];
      pa.u[2] = paw[ks][2]; pa.u[3] = paw[ks][3];
      v8bf v0 = *(const v8bf*)&vsb[(lq * 32 + ks * 16 + hi * 8) ^ sxv];
      v8bf v1 = *(const v8bf*)&vsb[((lq + 32) * 32 + ks * 16 + hi * 8) ^ sxv];
      o0 = __builtin_amdgcn_mfma_f32_32x32x16_bf16(pa.v, v0, o0, 0, 0, 0);
      o1 = __builtin_amdgcn_mfma_f32_32x32x16_bf16(pa.v, v1, o1, 0, 0, 0);
    }
    __builtin_amdgcn_s_setprio(0);
    if (kt < NKT - 1) __syncthreads();
  }

  // epilogue: partial O + (m in log2 units, l)
  const size_t S = (size_t)24 * 2048;
  const size_t srow = (size_t)zsplit * S + (size_t)bh * 2048;
  if (!hi) {
    Ml[(srow + qw0 + lq) * 2]     = mrun;
    Ml[(srow + qw0 + lq) * 2 + 1] = lsum;
  }
#pragma unroll
  for (int r = 0; r < 16; r++) {
    const int q = qw0 + (r & 3) + 8 * (r >> 2) + 4 * hi;
    Op[(srow + q) * 64 + lq]      = o0[r];
    Op[(srow + q) * 64 + 32 + lq] = o1[r];
  }
}

// ---------- combine the four split-K partials (m in log2 units) ----------
__global__ __launch_bounds__(256) void attn_combine(
    const float* __restrict__ Op, const float* __restrict__ Ml,
    __bf16* __restrict__ Oe) {
  const size_t S = (size_t)24 * 2048;
  int row = blockIdx.x * 4 + (threadIdx.x >> 6);   // bh*2048 + q, 0..49151
  int lane = threadIdx.x & 63;
  int bh = row >> 11, q = row & 2047;
  int b = bh / 12, h = bh - b * 12;
  float m[4], lv[4];
#pragma unroll
  for (int s = 0; s < 4; s++) {
    m[s]  = Ml[(s * S + row) * 2];
    lv[s] = Ml[(s * S + row) * 2 + 1];
  }
  float M = fmaxf(fmaxf(m[0], m[1]), fmaxf(m[2], m[3]));
  float num = 0.f, den = 0.f;
#pragma unroll
  for (int s = 0; s < 4; s++) {
    float a = __builtin_exp2f(m[s] - M);
    den += lv[s] * a;
    num += Op[(s * S + row) * 64 + lane] * a;
  }
  Oe[((size_t)(b * 2048 + q)) * 768 + h * 64 + lane] = (__bf16)(num / den);
}

// ---------- launcher ----------
extern "C" void kernel_launch(void* const* d_in, const int* in_sizes, int n_in,
                              void* d_out, int out_size, void* d_ws, size_t ws_size,
                              hipStream_t stream) {
  const float* x    = (const float*)d_in[0];
  const float* Wqkv = (const float*)d_in[1];
  const float* bqkv = (const float*)d_in[2];
  const float* Wout = (const float*)d_in[3];
  const float* bout = (const float*)d_in[4];
  float* out = (float*)d_out;
  char* ws = (char*)d_ws;

  unsigned short* Acat  = (unsigned short*)(ws + 0);          // 18.9 MB (dead after gemm_qkv)
  unsigned short* BcatT = (unsigned short*)(ws + 18874368);   // 1536 x 2304 (7.08 MB)
  unsigned short* WvT   = (unsigned short*)(ws + 25952256);   // 1.18 MB
  _Float16*       Qh    = (_Float16*)(ws + 67239936);         //  6.3 MB
  _Float16*       Kh    = (_Float16*)(ws + 86114304);         //  6.3 MB
  unsigned short* VT    = (unsigned short*)(ws + 104988672);  //  6.3 MB
  unsigned short* Oemb  = (unsigned short*)(ws + 111280128);  //  6.3 MB
  unsigned short* WoutT = (unsigned short*)(ws + 117571584);  //  1.2 MB
  // split-K partials alias the dead Acat/BcatT region (attn runs after gemm_qkv):
  float*          Opart = (float*)(ws + 0);                   // 4 x 12.58 MB = 50.3 MB
  float*          Mlpart= (float*)(ws + 52428800);            //  1.6 MB (dead region)

  prep_fused<<<dim3(21504), 256, 0, stream>>>(x, Wqkv, Wout, Acat, BcatT, WvT, WoutT);
  gemm_qkv<<<dim3(576), 256, 0, stream>>>(Acat, BcatT, WvT, bqkv, Qh, Kh, VT);
  attn<<<dim3(1536), 256, 0, stream>>>(Qh, Kh, VT, Opart, Mlpart);
  attn_combine<<<dim3(12288), 256, 0, stream>>>(Opart, Mlpart, (__bf16*)Oemb);
  gemm_out<<<dim3(384), 256, 0, stream>>>(Oemb, WoutT, bout, out);
}

// Round 14
// 138.946 us; speedup vs baseline: 2.0021x; 1.1263x over previous
//
#include <hip/hip_runtime.h>
#include <stdint.h>

#define LOG2E 1.44269504088896340736f

typedef __bf16 v8bf __attribute__((ext_vector_type(8)));
typedef _Float16 v8h __attribute__((ext_vector_type(8)));
typedef float f32x4 __attribute__((ext_vector_type(4)));
typedef float f32x16 __attribute__((ext_vector_type(16)));
typedef unsigned int v4u __attribute__((ext_vector_type(4)));
typedef unsigned int v2u __attribute__((ext_vector_type(2)));

// ---------- helpers ----------
__device__ __forceinline__ unsigned short f2bf(float f) {
  union { float f; uint32_t u; } v; v.f = f;
  uint32_t u = v.u;
  uint32_t r = (u + 0x7FFFu + ((u >> 16) & 1u)) >> 16;   // RN-even
  return (unsigned short)r;
}
__device__ __forceinline__ void gll16(const void* g, void* l) {
  __builtin_amdgcn_global_load_lds(
      (const __attribute__((address_space(1))) unsigned int*)g,
      (__attribute__((address_space(3))) unsigned int*)l, 16, 0, 0);
}
__device__ __forceinline__ uint32_t pk2(float a, float b) {
  union { __bf16 h[2]; uint32_t u; } x;
  x.h[0] = (__bf16)a; x.h[1] = (__bf16)b;
  return x.u;
}

// Permuted QKV column order c':
//   c' in [0,1536): h = c'>>7, j = c'&127  -> orig n = h*192 + j   (q|k)
//   c' in [1536,2304): h = (c'-1536)>>6, d = (..)&63 -> n = h*192+128+d (v)

// ---------- fused prep: Ah (x fp16), Whk (qk cols fp16, permuted), Wv (fp16), WoT (bf16) ----------
__global__ void prep_fused(const float* __restrict__ x, const float* __restrict__ Wqkv,
                           const float* __restrict__ Wout,
                           _Float16* __restrict__ Ah,
                           _Float16* __restrict__ Whk,
                           _Float16* __restrict__ Wv,
                           unsigned short* __restrict__ WoT) {
  const int t = threadIdx.x, f = blockIdx.x;
  if (f < 12288) {                    // Ah: x -> fp16
    int m = f / 3, n = (f - m * 3) * 256 + t;
    Ah[(size_t)m * 768 + n] = (_Float16)x[(size_t)m * 768 + n];
  } else if (f < 19200) {             // Wqkv columns (permuted)
    int g = f - 12288;
    int cp = g / 3, k = (g - cp * 3) * 256 + t;
    int n;
    if (cp < 1536) n = (cp >> 7) * 192 + (cp & 127);
    else           n = ((cp - 1536) >> 6) * 192 + 128 + ((cp - 1536) & 63);
    float v = Wqkv[(size_t)k * 2304 + n];
    if (cp < 1536) Whk[(size_t)cp * 768 + k] = (_Float16)v;
    else           Wv[(size_t)(cp - 1536) * 768 + k] = (_Float16)v;
  } else {                            // Wout^T plain bf16
    int g = f - 19200;
    int n = g / 3, k = (g - n * 3) * 256 + t;
    WoT[(size_t)n * 768 + k] = f2bf(Wout[(size_t)k * 768 + n]);
  }
}

// ---------- fused QKV GEMM (fp16, K=768) + split epilogues ----------
// f < 384: q|k path: C[m][c'] = Ah x Whk^T; epilogue -> fp16 Qh (x8*log2e) / Kh.
// f >= 384: v path TRANSPOSED: VT = Wv x Ah^T; epilogue -> bf16 VT[bh][dd][p].
__global__ __launch_bounds__(256) void gemm_qkv(
    const _Float16* __restrict__ Ah, const _Float16* __restrict__ Whk,
    const _Float16* __restrict__ Wv, const float* __restrict__ bqkv,
    _Float16* __restrict__ Qh, _Float16* __restrict__ Kh,
    unsigned short* __restrict__ VT) {
  __shared__ _Float16 As[128 * 32];
  __shared__ _Float16 Bs[128 * 32];
  const int t = threadIdx.x, f = blockIdx.x;
  const int w = t >> 6, l = t & 63, lr = l & 15, lg = l >> 4;
  const int wm = (w >> 1) * 64, wn = (w & 1) * 64;
  f32x4 acc[4][4] = {};

  if (f < 384) {
    // ---- q|k path ----
    const int xcd = f & 7, s = f >> 3;
    const int m0 = (xcd * 4 + (s & 3)) * 128;
    const int xt = s >> 2;                       // head 0..11
    const _Float16* Ap = Ah + (size_t)m0 * 768;
    const _Float16* Bp = Whk + (size_t)xt * 128 * 768;
    for (int kt = 0; kt < 24; ++kt) {
      const int k0 = kt << 5;
      const int c0 = t, c1 = t + 256;
      gll16(Ap + (size_t)(c0 >> 2) * 768 + k0 + ((c0 & 3) << 3), &As[c0 * 8]);
      gll16(Ap + (size_t)(c1 >> 2) * 768 + k0 + ((c1 & 3) << 3), &As[c1 * 8]);
      gll16(Bp + (size_t)(c0 >> 2) * 768 + k0 + ((c0 & 3) << 3), &Bs[c0 * 8]);
      gll16(Bp + (size_t)(c1 >> 2) * 768 + k0 + ((c1 & 3) << 3), &Bs[c1 * 8]);
      __syncthreads();
      v8h a[4], b[4];
#pragma unroll
      for (int i = 0; i < 4; i++) {
        a[i] = *(const v8h*)&As[(wm + i * 16 + lr) * 32 + lg * 8];
        b[i] = *(const v8h*)&Bs[(wn + i * 16 + lr) * 32 + lg * 8];
      }
#pragma unroll
      for (int i = 0; i < 4; i++)
#pragma unroll
        for (int j = 0; j < 4; j++)
          acc[i][j] = __builtin_amdgcn_mfma_f32_16x16x32_f16(a[i], b[j], acc[i][j], 0, 0, 0);
      __syncthreads();
    }
    // epilogue: single fp16 write (wave-uniform q/k branch: wn==0 -> q, else k)
#pragma unroll
    for (int j = 0; j < 4; j++) {
      const int jj = j * 16 + lr;                // 0..63 within q or k
      const float bv = bqkv[xt * 192 + wn + jj];
#pragma unroll
      for (int i = 0; i < 4; i++) {
#pragma unroll
        for (int r = 0; r < 4; r++) {
          const int m = m0 + wm + i * 16 + lg * 4 + r;
          const int b = m >> 11, p = m & 2047;
          size_t base = ((size_t)(b * 12 + xt) * 2048 + p) * 64;
          float val = acc[i][j][r] + bv;
          if (wn == 0) Qh[base + jj] = (_Float16)(val * (8.0f * LOG2E));
          else         Kh[base + jj] = (_Float16)val;
        }
      }
    }
  } else {
    // ---- v path, transposed: C'[d][m] = Wv x Ah^T ----
    const int g = f - 384;
    const int xcd = g & 7, s = g >> 3;           // s 0..23
    const int m0v = (xcd * 4 + (s & 3)) * 128;   // m-tile 0..31
    const int d0 = (s >> 2) * 128;               // d-tile 0..5
    for (int kt = 0; kt < 24; ++kt) {
      const int k0 = kt << 5;
      const int c0 = t, c1 = t + 256;
      gll16(Wv + (size_t)(d0 + (c0 >> 2)) * 768 + k0 + ((c0 & 3) << 3), &As[c0 * 8]);
      gll16(Wv + (size_t)(d0 + (c1 >> 2)) * 768 + k0 + ((c1 & 3) << 3), &As[c1 * 8]);
      gll16(Ah + (size_t)(m0v + (c0 >> 2)) * 768 + k0 + ((c0 & 3) << 3), &Bs[c0 * 8]);
      gll16(Ah + (size_t)(m0v + (c1 >> 2)) * 768 + k0 + ((c1 & 3) << 3), &Bs[c1 * 8]);
      __syncthreads();
      v8h a[4], b[4];
#pragma unroll
      for (int i = 0; i < 4; i++) {
        a[i] = *(const v8h*)&As[(wm + i * 16 + lr) * 32 + lg * 8];
        b[i] = *(const v8h*)&Bs[(wn + i * 16 + lr) * 32 + lg * 8];
      }
#pragma unroll
      for (int i = 0; i < 4; i++)
#pragma unroll
        for (int j = 0; j < 4; j++)
          acc[i][j] = __builtin_amdgcn_mfma_f32_16x16x32_f16(a[i], b[j], acc[i][j], 0, 0, 0);
      __syncthreads();
    }
    // epilogue: rows = d (h*64+dd), cols = m -> VT[bh][dd][p] (bf16), p coalesced
#pragma unroll
    for (int i = 0; i < 4; i++) {
#pragma unroll
      for (int r = 0; r < 4; r++) {
        const int drow = d0 + wm + i * 16 + lg * 4 + r;
        const int h = drow >> 6, dd = drow & 63;
        const float bv = bqkv[h * 192 + 128 + dd];
#pragma unroll
        for (int j = 0; j < 4; j++) {
          const int m = m0v + wn + j * 16 + lr;
          const int b = m >> 11, p = m & 2047;
          VT[((size_t)(b * 12 + h) * 64 + dd) * 2048 + p] = f2bf(acc[i][j][r] + bv);
        }
      }
    }
  }
}

// ---------- out-proj GEMM: 64x128 tiles, 384 blocks (bf16) ----------
__global__ __launch_bounds__(256) void gemm_out(
    const unsigned short* __restrict__ A, const unsigned short* __restrict__ B,
    const float* __restrict__ bias, float* __restrict__ C) {
  __shared__ unsigned short As[64 * 32];
  __shared__ unsigned short Bs[128 * 32];
  const int t = threadIdx.x, f = blockIdx.x;
  const int xcd = f & 7, s = f >> 3;             // s 0..47
  const int m0 = (xcd * 8 + (s & 7)) * 64;       // 64 m-tiles
  const int n0 = (s >> 3) * 128;                 // 6 n-tiles
  const int w = t >> 6, l = t & 63, lr = l & 15, lg = l >> 4;
  const int wm = (w >> 1) * 32, wn = (w & 1) * 64;
  f32x4 acc[2][4] = {};
  for (int kt = 0; kt < 24; ++kt) {
    const int k0 = kt << 5;
    gll16(A + (size_t)(m0 + (t >> 2)) * 768 + k0 + ((t & 3) << 3), &As[t * 8]);
    gll16(B + (size_t)(n0 + (t >> 2)) * 768 + k0 + ((t & 3) << 3), &Bs[t * 8]);
    gll16(B + (size_t)(n0 + 64 + (t >> 2)) * 768 + k0 + ((t & 3) << 3), &Bs[(t + 256) * 8]);
    __syncthreads();
    v8bf a[2], b[4];
#pragma unroll
    for (int i = 0; i < 2; i++)
      a[i] = *(const v8bf*)&As[(wm + i * 16 + lr) * 32 + lg * 8];
#pragma unroll
    for (int j = 0; j < 4; j++)
      b[j] = *(const v8bf*)&Bs[(wn + j * 16 + lr) * 32 + lg * 8];
#pragma unroll
    for (int i = 0; i < 2; i++)
#pragma unroll
      for (int j = 0; j < 4; j++)
        acc[i][j] = __builtin_amdgcn_mfma_f32_16x16x32_bf16(a[i], b[j], acc[i][j], 0, 0, 0);
    __syncthreads();
  }
#pragma unroll
  for (int i = 0; i < 2; i++) {
#pragma unroll
    for (int j = 0; j < 4; j++) {
      const int col = n0 + wn + j * 16 + lr;
      const float bv = bias[col];
#pragma unroll
      for (int r = 0; r < 4; r++) {
        const int row = m0 + wm + i * 16 + lg * 4 + r;
        C[(size_t)row * 768 + col] = acc[i][j][r] + bv;
      }
    }
  }
}

// ---------- flash attention: fp16 QK^T (K=64), KVBLK=32, split-K x2 ----------
// Flat grid 768 = 8 xcd x 6 pairGroups x 16 q-tiles -> EXACTLY 3 blocks/CU,
// zero tail. NKT=32 tiles of 32 keys per split. Softmax in log2 domain.
__global__ __launch_bounds__(256, 3) void attn(
    const _Float16* __restrict__ Qh, const _Float16* __restrict__ Kh,
    const unsigned short* __restrict__ VT,
    float* __restrict__ Op, float* __restrict__ Ml) {
  __shared__ __align__(16) _Float16 Ks[2][32 * 64];
  __shared__ __align__(16) unsigned short Vs[2][64 * 32];
  __shared__ float Al[4][32];
  const int t = threadIdx.x, w = t >> 6, l = t & 63;
  const int lq = l & 31, hi = l >> 5;
  const int f = blockIdx.x;
  const int xcd = f & 7, slot = f >> 3;
  const int p = xcd + 8 * (slot >> 4);      // 0..47: (bh,split) pair
  const int bh = p >> 1, zsplit = p & 1;
  const int q0 = (slot & 15) * 128;
  const int qw0 = q0 + w * 32;
  const int NKT = 32;
  const int ktBase = zsplit * 32;           // 32 key-tiles of 32 keys per split
  const _Float16* Qb = Qh + (size_t)bh * 2048 * 64;
  const _Float16* Kb = Kh + (size_t)bh * 2048 * 64;
  const unsigned short* Vb = VT + (size_t)bh * 64 * 2048;

  // swizzled LDS write offsets (element units)
  const int krow = t >> 3, kpart = t & 7;   // 8 chunks per 64-elem fp16 K row
  const int kwofs = (krow * 64 + kpart * 8) ^ ((krow & 7) << 3);
  const int vd = t >> 2, vpart = t & 3;     // 4 chunks per 32-elem V row
  const int vwofs = (vd * 32 + vpart * 8) ^ ((vd & 3) << 3);

  // linear global source pointers (coalesced), bumped per kt
  const char* gK = (const char*)Kb + (size_t)ktBase * 4096 + (size_t)t * 16;
  const char* gV = (const char*)Vb + (size_t)vd * 4096 + (size_t)vpart * 16
                   + (size_t)ktBase * 64;

  v4u kreg, vreg;
  kreg = *(const v4u*)gK;
  vreg = *(const v4u*)gV;
  *(v4u*)&Ks[0][kwofs] = kreg;
  *(v4u*)&Vs[0][vwofs] = vreg;
  gK += 4096; gV += 64;
  kreg = *(const v4u*)gK;
  vreg = *(const v4u*)gV;

  // Q B-frags (fp16): lane holds Q[qw0+lq][ks*16 + hi*8 .. +7]
  v8h qf[4];
#pragma unroll
  for (int ks = 0; ks < 4; ++ks)
    qf[ks] = *(const v8h*)(Qb + (size_t)(qw0 + lq) * 64 + ks * 16 + hi * 8);

  f32x16 o0 = {}, o1 = {};
  float mrun = -1e30f, lsum = 0.f;
  const int sxk = (lq & 7) << 3;            // K read swizzle (rows = lq)
  const int sxv = (lq & 3) << 3;            // V read swizzle (rows = lq, lq+32)
  __syncthreads();

  for (int kt = 0; kt < NKT; ++kt) {
    const _Float16* ksb = &Ks[kt & 1][0];
    const unsigned short* vsb = &Vs[kt & 1][0];
    _Float16* ksw = &Ks[(kt & 1) ^ 1][0];
    unsigned short* vsw = &Vs[(kt & 1) ^ 1][0];

    // S^T(log2) = K Q^T  (fp16, K=64 -> 4 MFMA)
    f32x16 s = {};
    __builtin_amdgcn_s_setprio(1);
#pragma unroll
    for (int ks = 0; ks < 4; ++ks) {
      v8h ka = *(const v8h*)&ksb[(lq * 64 + ks * 16 + hi * 8) ^ sxk];
      s = __builtin_amdgcn_mfma_f32_32x32x16_f16(ka, qf[ks], s, 0, 0, 0);
    }
    __builtin_amdgcn_s_setprio(0);

    // stage tile kt+1 into the other buffer (overlaps compute)
    if (kt < NKT - 1) {
      *(v4u*)&ksw[kwofs] = kreg;
      *(v4u*)&vsw[vwofs] = vreg;
    }
    if (kt < NKT - 2) {
      gK += 4096; gV += 64;
      kreg = *(const v4u*)gK;
      vreg = *(const v4u*)gV;
    }

    // lane-local max (tree) + one half-swap
    float tm[8];
#pragma unroll
    for (int i = 0; i < 8; i++) tm[i] = fmaxf(s[i], s[i + 8]);
#pragma unroll
    for (int i = 0; i < 4; i++) tm[i] = fmaxf(tm[i], tm[i + 4]);
    float pmax = fmaxf(fmaxf(tm[0], tm[1]), fmaxf(tm[2], tm[3]));
    {
      v2u r = __builtin_amdgcn_permlane32_swap(__float_as_uint(pmax),
                                               __float_as_uint(pmax), false, false);
      pmax = fmaxf(__uint_as_float(r.x), __uint_as_float(r.y));
    }

    // T13 defer-max, THR=32 (log2 units)
    if (__any(pmax > mrun + 32.f)) {
      float mnew = fmaxf(mrun, pmax);
      float a = __builtin_exp2f(mrun - mnew);
      mrun = mnew;
      lsum *= a;
      if (!hi) Al[w][lq] = a;
#pragma unroll
      for (int r = 0; r < 16; r++) {
        float ar = Al[w][(r & 3) + 8 * (r >> 2) + 4 * hi];
        o0[r] *= ar; o1[r] *= ar;
      }
    }

    // P = exp2(S - m) in-place, tree sum, pack PV A-frags
#pragma unroll
    for (int i = 0; i < 16; i++) s[i] = __builtin_exp2f(s[i] - mrun);
    {
      float a0 = (s[0] + s[8]) + (s[1] + s[9]);
      float a1 = (s[2] + s[10]) + (s[3] + s[11]);
      float a2 = (s[4] + s[12]) + (s[5] + s[13]);
      float a3 = (s[6] + s[14]) + (s[7] + s[15]);
      float ps = (a0 + a1) + (a2 + a3);
      v2u r = __builtin_amdgcn_permlane32_swap(__float_as_uint(ps),
                                               __float_as_uint(ps), false, false);
      lsum += __uint_as_float(r.x) + __uint_as_float(r.y);
    }
    uint32_t paw[2][4];
    {
      v2u r0 = __builtin_amdgcn_permlane32_swap(pk2(s[0], s[1]), pk2(s[4], s[5]), false, false);
      v2u r1 = __builtin_amdgcn_permlane32_swap(pk2(s[2], s[3]), pk2(s[6], s[7]), false, false);
      paw[0][0] = r0.x; paw[0][2] = r0.y; paw[0][1] = r1.x; paw[0][3] = r1.y;
      v2u r2 = __builtin_amdgcn_permlane32_swap(pk2(s[8], s[9]), pk2(s[12], s[13]), false, false);
      v2u r3 = __builtin_amdgcn_permlane32_swap(pk2(s[10], s[11]), pk2(s[14], s[15]), false, false);
      paw[1][0] = r2.x; paw[1][2] = r2.y; paw[1][1] = r3.x; paw[1][3] = r3.y;
    }

    // O += P V  (bf16)
    __builtin_amdgcn_s_setprio(1);
#pragma unroll
    for (int ks = 0; ks < 2; ++ks) {
      union { uint32_t u[4]; v8bf v; } pa;
      pa.u[0] = paw[ks][0]; pa.u[1] = paw[ks][1];
      pa.u[2] = paw[ks][2]; pa.u[3] = paw[ks][3];
      v8bf v0 = *(const v8bf*)&vsb[(lq * 32 + ks * 16 + hi * 8) ^ sxv];
      v8bf v1 = *(const v8bf*)&vsb[((lq + 32) * 32 + ks * 16 + hi * 8) ^ sxv];
      o0 = __builtin_amdgcn_mfma_f32_32x32x16_bf16(pa.v, v0, o0, 0, 0, 0);
      o1 = __builtin_amdgcn_mfma_f32_32x32x16_bf16(pa.v, v1, o1, 0, 0, 0);
    }
    __builtin_amdgcn_s_setprio(0);
    if (kt < NKT - 1) __syncthreads();
  }

  // epilogue: partial O + (m in log2 units, l)
  const size_t S = (size_t)24 * 2048;
  const size_t srow = (size_t)zsplit * S + (size_t)bh * 2048;
  if (!hi) {
    Ml[(srow + qw0 + lq) * 2]     = mrun;
    Ml[(srow + qw0 + lq) * 2 + 1] = lsum;
  }
#pragma unroll
  for (int r = 0; r < 16; r++) {
    const int q = qw0 + (r & 3) + 8 * (r >> 2) + 4 * hi;
    Op[(srow + q) * 64 + lq]      = o0[r];
    Op[(srow + q) * 64 + 32 + lq] = o1[r];
  }
}

// ---------- combine the two split-K partials (m in log2 units) ----------
__global__ __launch_bounds__(256) void attn_combine(
    const float* __restrict__ Op, const float* __restrict__ Ml,
    __bf16* __restrict__ Oe) {
  const size_t S = (size_t)24 * 2048;
  int row = blockIdx.x * 4 + (threadIdx.x >> 6);
  int lane = threadIdx.x & 63;
  int bh = row >> 11, q = row & 2047;
  int b = bh / 12, h = bh - b * 12;
  float m1 = Ml[(size_t)row * 2], l1 = Ml[(size_t)row * 2 + 1];
  float m2 = Ml[(S + row) * 2],   l2 = Ml[(S + row) * 2 + 1];
  float M = fmaxf(m1, m2);
  float a1 = __builtin_exp2f(m1 - M);
  float a2 = __builtin_exp2f(m2 - M);
  float rinv = 1.0f / (l1 * a1 + l2 * a2);
  float o1 = Op[(size_t)row * 64 + lane];
  float o2 = Op[S * 64 + (size_t)row * 64 + lane];
  Oe[((size_t)(b * 2048 + q)) * 768 + h * 64 + lane] = (__bf16)((o1 * a1 + o2 * a2) * rinv);
}

// ---------- launcher ----------
extern "C" void kernel_launch(void* const* d_in, const int* in_sizes, int n_in,
                              void* d_out, int out_size, void* d_ws, size_t ws_size,
                              hipStream_t stream) {
  const float* x    = (const float*)d_in[0];
  const float* Wqkv = (const float*)d_in[1];
  const float* bqkv = (const float*)d_in[2];
  const float* Wout = (const float*)d_in[3];
  const float* bout = (const float*)d_in[4];
  float* out = (float*)d_out;
  char* ws = (char*)d_ws;

  _Float16*       Ah    = (_Float16*)(ws + 0);                // 6.3 MB (dead after gemm_qkv)
  _Float16*       Whk   = (_Float16*)(ws + 18874368);         // 2.36 MB (dead after gemm_qkv)
  _Float16*       Wv    = (_Float16*)(ws + 25952256);         // 1.18 MB (dead after gemm_qkv)
  _Float16*       Qh    = (_Float16*)(ws + 67239936);         // 6.3 MB
  _Float16*       Kh    = (_Float16*)(ws + 86114304);         // 6.3 MB
  unsigned short* VT    = (unsigned short*)(ws + 104988672);  // 6.3 MB
  unsigned short* Oemb  = (unsigned short*)(ws + 111280128);  // 6.3 MB
  unsigned short* WoT   = (unsigned short*)(ws + 117571584);  // 1.2 MB
  // split-K partials alias the dead Ah/Whk/Wv region (attn runs after gemm_qkv):
  float*          Opart = (float*)(ws + 0);                   // 2 x 12.58 MB = 25.2 MB
  float*          Mlpart= (float*)(ws + 50331648);            // 0.8 MB (dead region)

  prep_fused<<<dim3(21504), 256, 0, stream>>>(x, Wqkv, Wout, Ah, Whk, Wv, WoT);
  gemm_qkv<<<dim3(576), 256, 0, stream>>>(Ah, Whk, Wv, bqkv, Qh, Kh, VT);
  attn<<<dim3(768), 256, 0, stream>>>(Qh, Kh, VT, Opart, Mlpart);
  attn_combine<<<dim3(12288), 256, 0, stream>>>(Opart, Mlpart, (__bf16*)Oemb);
  gemm_out<<<dim3(384), 256, 0, stream>>>(Oemb, WoT, bout, out);
}